// Round 2
// baseline (348.575 us; speedup 1.0000x reference)
//
#include <hip/hip_runtime.h>
#include <stdint.h>
#include <math.h>

typedef unsigned short u16;
typedef __attribute__((ext_vector_type(8))) short short8;   // 8 bf16 (4 VGPRs)
typedef __attribute__((ext_vector_type(4))) short short4v;  // 4 bf16 (2 VGPRs)
typedef __attribute__((ext_vector_type(4))) float f32x4;

#define DEVFN static __device__ __forceinline__

DEVFN float bf2f(short b) {
  union { unsigned int i; float f; } u;
  u.i = ((unsigned int)(unsigned short)b) << 16;
  return u.f;
}
DEVFN short f2bf(float f) {
  union { float f; unsigned int i; } u; u.f = f;
  unsigned int r = u.i + 0x7fffu + ((u.i >> 16) & 1u);  // RNE
  return (short)(r >> 16);
}

DEVFN f32x4 mfma32(short8 a, short8 b, f32x4 c) {
  return __builtin_amdgcn_mfma_f32_16x16x32_bf16(a, b, c, 0, 0, 0);
}
DEVFN f32x4 mfma16(short4v a, short4v b, f32x4 c) {
#if defined(__HIP_DEVICE_COMPILE__)
  return __builtin_amdgcn_mfma_f32_16x16x16bf16_1k(a, b, c, 0, 0, 0);
#else
  (void)a; (void)b; return c;  // host stub, never executed
#endif
}

typedef const __attribute__((address_space(1))) unsigned int* gp_t;
typedef __attribute__((address_space(3))) unsigned int* lp_t;
DEVFN void async_copy16(u16* lds, const u16* g) {
  __builtin_amdgcn_global_load_lds((gp_t)(const void*)g, (lp_t)(void*)lds, 16, 0, 0);
}

// ---------------- f32 -> bf16 cast ----------------
__global__ void cast_kernel(const float* __restrict__ in, u16* __restrict__ out, int n4) {
  int i = blockIdx.x * blockDim.x + threadIdx.x;
  if (i < n4) {
    f32x4 v = ((const f32x4*)in)[i];
    short4v o;
    o[0] = f2bf(v[0]); o[1] = f2bf(v[1]); o[2] = f2bf(v[2]); o[3] = f2bf(v[3]);
    ((short4v*)out)[i] = o;
  }
}

// ---------------- row-wise RMSNorm (bf16 in/out, f32 weight) ----------------
// blockDim.x = len/8 (must be multiple of 64)
__global__ void rmsnorm_kernel(const u16* __restrict__ in, int istride,
                               u16* __restrict__ out, int ostride,
                               const float* __restrict__ w, int len) {
  const int row = blockIdx.x, t = threadIdx.x;
  short8 v = *(const short8*)(in + (size_t)row * istride + t * 8);
  float f[8]; float ss = 0.f;
#pragma unroll
  for (int j = 0; j < 8; ++j) { f[j] = bf2f(v[j]); ss += f[j] * f[j]; }
#pragma unroll
  for (int off = 1; off < 64; off <<= 1) ss += __shfl_xor(ss, off);
  __shared__ float red[8];
  int nw = (int)blockDim.x >> 6;
  if ((t & 63) == 0) red[t >> 6] = ss;
  __syncthreads();
  ss = 0.f;
  for (int i = 0; i < nw; ++i) ss += red[i];
  float r = rsqrtf(ss / (float)len + 1e-6f);
  const float* wp = w + t * 8;
  short8 ov;
#pragma unroll
  for (int j = 0; j < 8; ++j) ov[j] = f2bf(f[j] * r * wp[j]);
  *(short8*)(out + (size_t)row * ostride + t * 8) = ov;
}

// ---------------- RoPE (interleaved-perm variant) ----------------
// grid = B*S rows, block = 64
__global__ void rope_kernel(const u16* __restrict__ q, const u16* __restrict__ ckv,
                            const int* __restrict__ pos_ids,
                            u16* __restrict__ qpe, u16* __restrict__ kpe) {
  const int row = blockIdx.x;
  const int t = threadIdx.x;
  const float pos = (float)pos_ids[row];
  const float L2TH = 13.287712379549449f;  // log2(10000)
  if (t < 32) {
    int i = t;
    float inv = exp2f(-L2TH * (float)i / 32.0f);
    float sv, cv; sincosf(pos * inv, &sv, &cv);
    float x0 = bf2f(ckv[(size_t)row * 576 + 512 + 2 * i]);
    float x1 = bf2f(ckv[(size_t)row * 576 + 512 + 2 * i + 1]);
    kpe[(size_t)row * 64 + i]      = (u16)f2bf(x0 * cv - x1 * sv);
    kpe[(size_t)row * 64 + 32 + i] = (u16)f2bf(x1 * cv + x0 * sv);
  }
#pragma unroll
  for (int j = 0; j < 8; ++j) {
    int idx = t + 64 * j;
    int hh = idx >> 5, i = idx & 31;
    float inv = exp2f(-L2TH * (float)i / 32.0f);
    float sv, cv; sincosf(pos * inv, &sv, &cv);
    const u16* base = q + (size_t)row * 3072 + hh * 192 + 128;
    float x0 = bf2f(base[2 * i]), x1 = bf2f(base[2 * i + 1]);
    u16* ob = qpe + ((size_t)row * 16 + hh) * 64;
    ob[i]      = (u16)f2bf(x0 * cv - x1 * sv);
    ob[32 + i] = (u16)f2bf(x1 * cv + x0 * sv);
  }
}

// ---------------- GEMM: C[m,n] = sum_k A[m,k]*B[n,k], bf16 in, f32 acc ----------------
// 128x128 tile, BK=64, 4 waves (2x2 of 64x64), global_load_lds + XOR swizzle.
template <bool OUT_F32>
__global__ __launch_bounds__(256) void gemm_bt(const u16* __restrict__ A,
                                               const u16* __restrict__ B,
                                               void* __restrict__ C,
                                               int M, int N, int K, int ldc) {
  __shared__ u16 As[128 * 64];
  __shared__ u16 Bs[128 * 64];
  const int tid = threadIdx.x;
  const int w = tid >> 6, l = tid & 63;
  const int lq = l & 15, lg = l >> 4;
  const int wm = (w >> 1) << 6, wn = (w & 1) << 6;
  const int m0 = blockIdx.y << 7, n0 = blockIdx.x << 7;

  f32x4 acc[4][4];
#pragma unroll
  for (int i = 0; i < 4; ++i)
#pragma unroll
    for (int j = 0; j < 4; ++j) acc[i][j] = (f32x4){0.f, 0.f, 0.f, 0.f};

  for (int k0 = 0; k0 < K; k0 += 64) {
    // stage A: 128 rows x 64 cols, linear LDS dest, inverse-swizzled global src
#pragma unroll
    for (int i = 0; i < 4; ++i) {
      int c = i * 256 + tid;            // 16B-chunk id 0..1023
      int row = c >> 3, pc = c & 7;
      int lc = pc ^ (row & 7);          // logical col-chunk
      async_copy16(&As[c * 8], A + (size_t)(m0 + row) * K + k0 + lc * 8);
    }
#pragma unroll
    for (int i = 0; i < 4; ++i) {
      int c = i * 256 + tid;
      int row = c >> 3, pc = c & 7;
      int lc = pc ^ (row & 7);
      int br = n0 + row; br = br < N ? br : N - 1;   // clamp for N=576 tile
      async_copy16(&Bs[c * 8], B + (size_t)br * K + k0 + lc * 8);
    }
    asm volatile("s_waitcnt vmcnt(0)" ::: "memory");
    __syncthreads();

#pragma unroll
    for (int ks = 0; ks < 2; ++ks) {
      short8 af[4], bfr[4];
#pragma unroll
      for (int mi = 0; mi < 4; ++mi) {
        int row = wm + mi * 16 + lq;
        int ch = ((ks << 2) | lg) ^ (row & 7);       // swizzled read
        af[mi] = *(const short8*)&As[row * 64 + ch * 8];
      }
#pragma unroll
      for (int ni = 0; ni < 4; ++ni) {
        int row = wn + ni * 16 + lq;
        int ch = ((ks << 2) | lg) ^ (row & 7);
        bfr[ni] = *(const short8*)&Bs[row * 64 + ch * 8];
      }
#pragma unroll
      for (int mi = 0; mi < 4; ++mi)
#pragma unroll
        for (int ni = 0; ni < 4; ++ni)
          acc[mi][ni] = mfma32(af[mi], bfr[ni], acc[mi][ni]);
    }
    __syncthreads();
  }

  // epilogue: D layout col=lane&15, row=(lane>>4)*4+reg
#pragma unroll
  for (int mi = 0; mi < 4; ++mi) {
#pragma unroll
    for (int ni = 0; ni < 4; ++ni) {
      int col = n0 + wn + ni * 16 + lq;
      if (col < N) {
#pragma unroll
        for (int r = 0; r < 4; ++r) {
          int rowm = m0 + wm + mi * 16 + lg * 4 + r;
          if constexpr (OUT_F32)
            ((float*)C)[(size_t)rowm * ldc + col] = acc[mi][ni][r];
          else
            ((u16*)C)[(size_t)rowm * ldc + col] = (u16)f2bf(acc[mi][ni][r]);
        }
      }
    }
  }
}

// ---------------- causal flash attention ----------------
// grid (16, NH, B), block 256 (4 waves); wave w handles q rows [bx*64 + w*16, +16)
// (contiguous 64-q chunk per block -> co-resident waves have nkt within 3 of
//  each other; the old w*256+bx*16 mapping made block time = worst wave)
// swapped QK^T: S^T = mfma(K_frag, Q_frag) -> stats lane-local per q (col = lane&15)
// PV: out^T = mfma16(V^T_frag, P^T_frag) -> q stays in col = lane&15
__global__ __launch_bounds__(256) void attn_kernel(const u16* __restrict__ q,
                                                   const u16* __restrict__ qpe,
                                                   const u16* __restrict__ kv,
                                                   const u16* __restrict__ kpe,
                                                   u16* __restrict__ o) {
  const int S = 1024;
  const int w = threadIdx.x >> 6, l = threadIdx.x & 63;
  const int lq = l & 15, lg = l >> 4;
  const int h = blockIdx.y, b = blockIdx.z;
  const int q0 = blockIdx.x * 64 + w * 16;
  const size_t qrow = (size_t)b * S + q0 + lq;

  short8 qf[6];
#pragma unroll
  for (int c = 0; c < 4; ++c)
    qf[c] = *(const short8*)(q + qrow * 3072 + h * 192 + c * 32 + lg * 8);
#pragma unroll
  for (int c = 0; c < 2; ++c)
    qf[4 + c] = *(const short8*)(qpe + (qrow * 16 + h) * 64 + c * 32 + lg * 8);

  const float scl = 0.07216878364870323f * 1.4426950408889634f;  // 192^-0.5 * log2(e)
  float m2 = -INFINITY, lsum = 0.f;
  f32x4 oac[8];
#pragma unroll
  for (int dt = 0; dt < 8; ++dt) oac[dt] = (f32x4){0.f, 0.f, 0.f, 0.f};

  const int nkt = (q0 >> 4) + 1;
  for (int kt = 0; kt < nkt; ++kt) {
    const size_t krow = (size_t)b * S + kt * 16 + lq;
    f32x4 sac = (f32x4){0.f, 0.f, 0.f, 0.f};
    const u16* kbase = kv + krow * 4096 + h * 256;
#pragma unroll
    for (int c = 0; c < 4; ++c)
      sac = mfma32(*(const short8*)(kbase + c * 32 + lg * 8), qf[c], sac);
#pragma unroll
    for (int c = 0; c < 2; ++c)
      sac = mfma32(*(const short8*)(kpe + krow * 64 + c * 32 + lg * 8), qf[4 + c], sac);

    // S^T layout: k = kt*16 + lg*4 + r (row), q = q0 + lq (col)
    float s2[4];
#pragma unroll
    for (int r = 0; r < 4; ++r) {
      int kidx = kt * 16 + lg * 4 + r;
      s2[r] = (kidx <= q0 + lq) ? sac[r] * scl : -INFINITY;
    }
    float mt = fmaxf(fmaxf(s2[0], s2[1]), fmaxf(s2[2], s2[3]));
    mt = fmaxf(mt, __shfl_xor(mt, 16));
    mt = fmaxf(mt, __shfl_xor(mt, 32));
    float mnew = fmaxf(m2, mt);
    float resc = exp2f(m2 - mnew);   // 0 on first tile (m2 = -inf)
    float p[4], psum = 0.f;
#pragma unroll
    for (int r = 0; r < 4; ++r) { p[r] = exp2f(s2[r] - mnew); psum += p[r]; }
    psum += __shfl_xor(psum, 16);
    psum += __shfl_xor(psum, 32);
    lsum = lsum * resc + psum;
    m2 = mnew;

    short4v pf;
#pragma unroll
    for (int r = 0; r < 4; ++r) pf[r] = f2bf(p[r]);
#pragma unroll
    for (int dt = 0; dt < 8; ++dt) oac[dt] *= resc;

    // PV: out^T[d,q] += sum_k V[k,d] * P^T[k,q]
#pragma unroll
    for (int dt = 0; dt < 8; ++dt) {
      short4v vf;
#pragma unroll
      for (int i = 0; i < 4; ++i)
        vf[i] = (short)kv[((size_t)b * S + kt * 16 + lg * 4 + i) * 4096 + h * 256 + 128 + dt * 16 + lq];
      oac[dt] = mfma16(vf, pf, oac[dt]);
    }
  }

  float inv = 1.f / lsum;
#pragma unroll
  for (int dt = 0; dt < 8; ++dt)
#pragma unroll
    for (int r = 0; r < 4; ++r)
      o[((size_t)b * S + q0 + lq) * 2048 + h * 128 + dt * 16 + lg * 4 + r] =
          (u16)f2bf(oac[dt][r] * inv);
}

// ---------------- host launcher ----------------
extern "C" void kernel_launch(void* const* d_in, const int* in_sizes, int n_in,
                              void* d_out, int out_size, void* d_ws, size_t ws_size,
                              hipStream_t stream) {
  const float* h_in  = (const float*)d_in[0];
  const int*   pos   = (const int*)d_in[1];
  const float* qaw   = (const float*)d_in[2];
  const float* qaln  = (const float*)d_in[3];
  const float* qbw   = (const float*)d_in[4];
  const float* kvaw  = (const float*)d_in[5];
  const float* kvaln = (const float*)d_in[6];
  const float* kvbw  = (const float*)d_in[7];
  const float* ow    = (const float*)d_in[8];
  float* out = (float*)d_out;

  const int M = 2048;  // B*S
  char* p = (char*)d_ws;
  auto alloc = [&](size_t bytes) {
    char* r = p;
    p += (bytes + 255) & ~(size_t)255;
    return (u16*)r;
  };
  u16* h_bf = alloc((size_t)M * 2048 * 2);        // also reused as attno later
  u16* W    = alloc((size_t)3072 * 1536 * 2);     // shared weight staging (max 9.4MB)
  u16* qa   = alloc((size_t)M * 1536 * 2);        // also hosts ckv+ckvn after gemm2
  u16* qbuf = alloc((size_t)M * 3072 * 2);
  u16* kvb  = alloc((size_t)M * 4096 * 2);
  u16* qpe  = alloc((size_t)M * 16 * 64 * 2);
  u16* kpe  = alloc((size_t)M * 64 * 2);
  // overlays (lifetimes verified: qa dead after gemm2; h_bf dead after gemm3)
  u16* ckv  = qa;                                  // M x 576
  u16* ckvn = qa + (size_t)M * 576;                // M x 512
  u16* attno = h_bf;                               // M x 2048

  dim3 blk(256);

  // 1) cast hidden + q_a_w, GEMM1, rmsnorm(q)
  cast_kernel<<<4096, blk, 0, stream>>>(h_in, h_bf, 1048576);
  cast_kernel<<<3072, blk, 0, stream>>>(qaw, W, 786432);
  gemm_bt<false><<<dim3(12, 16), blk, 0, stream>>>(h_bf, W, qa, M, 1536, 2048, 1536);
  rmsnorm_kernel<<<2048, 192, 0, stream>>>(qa, 1536, qa, 1536, qaln, 1536);

  // 2) GEMM2 -> q
  cast_kernel<<<4608, blk, 0, stream>>>(qbw, W, 1179648);
  gemm_bt<false><<<dim3(24, 16), blk, 0, stream>>>(qa, W, qbuf, M, 3072, 1536, 3072);

  // 3) GEMM3 -> ckv (overlays qa region; qa is dead now), rmsnorm(kv)
  cast_kernel<<<1152, blk, 0, stream>>>(kvaw, W, 294912);
  gemm_bt<false><<<dim3(5, 16), blk, 0, stream>>>(h_bf, W, ckv, M, 576, 2048, 576);
  rmsnorm_kernel<<<2048, 64, 0, stream>>>(ckv, 576, ckvn, 512, kvaln, 512);

  // 4) GEMM4 -> kv
  cast_kernel<<<2048, blk, 0, stream>>>(kvbw, W, 524288);
  gemm_bt<false><<<dim3(32, 16), blk, 0, stream>>>(ckvn, W, kvb, M, 4096, 512, 4096);

  // 5) RoPE (q_pe, k_pe)
  rope_kernel<<<2048, 64, 0, stream>>>(qbuf, ckv, pos, qpe, kpe);

  // 6) attention -> attno (overlays h_bf; h_bf dead after gemm3)
  attn_kernel<<<dim3(16, 16, 2), blk, 0, stream>>>(qbuf, qpe, kvb, kpe, attno);

  // 7) output projection -> d_out (f32)
  cast_kernel<<<4096, blk, 0, stream>>>(ow, W, 1048576);
  gemm_bt<true><<<dim3(16, 16), blk, 0, stream>>>(attno, W, out, M, 2048, 2048, 2048);
}

// Round 4
// 264.780 us; speedup vs baseline: 1.3165x; 1.3165x over previous
//
#include <hip/hip_runtime.h>
#include <stdint.h>
#include <math.h>

typedef unsigned short u16;
typedef __attribute__((ext_vector_type(8))) short short8;   // 8 bf16 (4 VGPRs)
typedef __attribute__((ext_vector_type(4))) short short4v;  // 4 bf16 (2 VGPRs)
typedef __attribute__((ext_vector_type(4))) float f32x4;

#define DEVFN static __device__ __forceinline__

DEVFN float bf2f(short b) {
  union { unsigned int i; float f; } u;
  u.i = ((unsigned int)(unsigned short)b) << 16;
  return u.f;
}
DEVFN short f2bf(float f) {
  union { float f; unsigned int i; } u; u.f = f;
  unsigned int r = u.i + 0x7fffu + ((u.i >> 16) & 1u);  // RNE
  return (short)(r >> 16);
}

DEVFN f32x4 mfma32(short8 a, short8 b, f32x4 c) {
  return __builtin_amdgcn_mfma_f32_16x16x32_bf16(a, b, c, 0, 0, 0);
}
DEVFN f32x4 mfma16(short4v a, short4v b, f32x4 c) {
#if defined(__HIP_DEVICE_COMPILE__)
  return __builtin_amdgcn_mfma_f32_16x16x16bf16_1k(a, b, c, 0, 0, 0);
#else
  (void)a; (void)b; return c;  // host stub, never executed
#endif
}

typedef const __attribute__((address_space(1))) unsigned int* gp_t;
typedef __attribute__((address_space(3))) unsigned int* lp_t;
typedef const __attribute__((address_space(3))) u16* lds_cp;
DEVFN void async_copy16(u16* lds, const u16* g) {
  __builtin_amdgcn_global_load_lds((gp_t)(const void*)g, (lp_t)(void*)lds, 16, 0, 0);
}
// tr-read: 16-lane group reads a 4x16 bf16 row-major tile (128B); lane must pass
// subtile_base + (lane&15)*8 bytes; output lane = column (lane&15), elem j = row j.
DEVFN short4v tr_read16(const u16* p) {
  short4v r;
  asm volatile("ds_read_b64_tr_b16 %0, %1" : "=v"(r) : "v"((lds_cp)(const void*)p));
  return r;
}

// ---------------- f32 -> bf16 cast ----------------
__global__ void cast_kernel(const float* __restrict__ in, u16* __restrict__ out, int n4) {
  int i = blockIdx.x * blockDim.x + threadIdx.x;
  if (i < n4) {
    f32x4 v = ((const f32x4*)in)[i];
    short4v o;
    o[0] = f2bf(v[0]); o[1] = f2bf(v[1]); o[2] = f2bf(v[2]); o[3] = f2bf(v[3]);
    ((short4v*)out)[i] = o;
  }
}

// ---------------- row-wise RMSNorm (bf16 in/out, f32 weight) ----------------
__global__ void rmsnorm_kernel(const u16* __restrict__ in, int istride,
                               u16* __restrict__ out, int ostride,
                               const float* __restrict__ w, int len) {
  const int row = blockIdx.x, t = threadIdx.x;
  short8 v = *(const short8*)(in + (size_t)row * istride + t * 8);
  float f[8]; float ss = 0.f;
#pragma unroll
  for (int j = 0; j < 8; ++j) { f[j] = bf2f(v[j]); ss += f[j] * f[j]; }
#pragma unroll
  for (int off = 1; off < 64; off <<= 1) ss += __shfl_xor(ss, off);
  __shared__ float red[8];
  int nw = (int)blockDim.x >> 6;
  if ((t & 63) == 0) red[t >> 6] = ss;
  __syncthreads();
  ss = 0.f;
  for (int i = 0; i < nw; ++i) ss += red[i];
  float r = rsqrtf(ss / (float)len + 1e-6f);
  const float* wp = w + t * 8;
  short8 ov;
#pragma unroll
  for (int j = 0; j < 8; ++j) ov[j] = f2bf(f[j] * r * wp[j]);
  *(short8*)(out + (size_t)row * ostride + t * 8) = ov;
}

// ---------------- RoPE (interleaved-perm variant) ----------------
__global__ void rope_kernel(const u16* __restrict__ q, const u16* __restrict__ ckv,
                            const int* __restrict__ pos_ids,
                            u16* __restrict__ qpe, u16* __restrict__ kpe) {
  const int row = blockIdx.x;
  const int t = threadIdx.x;
  const float pos = (float)pos_ids[row];
  const float L2TH = 13.287712379549449f;  // log2(10000)
  if (t < 32) {
    int i = t;
    float inv = exp2f(-L2TH * (float)i / 32.0f);
    float sv, cv; sincosf(pos * inv, &sv, &cv);
    float x0 = bf2f(ckv[(size_t)row * 576 + 512 + 2 * i]);
    float x1 = bf2f(ckv[(size_t)row * 576 + 512 + 2 * i + 1]);
    kpe[(size_t)row * 64 + i]      = (u16)f2bf(x0 * cv - x1 * sv);
    kpe[(size_t)row * 64 + 32 + i] = (u16)f2bf(x1 * cv + x0 * sv);
  }
#pragma unroll
  for (int j = 0; j < 8; ++j) {
    int idx = t + 64 * j;
    int hh = idx >> 5, i = idx & 31;
    float inv = exp2f(-L2TH * (float)i / 32.0f);
    float sv, cv; sincosf(pos * inv, &sv, &cv);
    const u16* base = q + (size_t)row * 3072 + hh * 192 + 128;
    float x0 = bf2f(base[2 * i]), x1 = bf2f(base[2 * i + 1]);
    u16* ob = qpe + ((size_t)row * 16 + hh) * 64;
    ob[i]      = (u16)f2bf(x0 * cv - x1 * sv);
    ob[32 + i] = (u16)f2bf(x1 * cv + x0 * sv);
  }
}

// ---------------- GEMM: C[m,n] = sum_k A[m,k]*B[n,k], bf16 in, f32 acc ----------------
template <bool OUT_F32>
__global__ __launch_bounds__(256) void gemm_bt(const u16* __restrict__ A,
                                               const u16* __restrict__ B,
                                               void* __restrict__ C,
                                               int M, int N, int K, int ldc) {
  __shared__ u16 As[128 * 64];
  __shared__ u16 Bs[128 * 64];
  const int tid = threadIdx.x;
  const int w = tid >> 6, l = tid & 63;
  const int lq = l & 15, lg = l >> 4;
  const int wm = (w >> 1) << 6, wn = (w & 1) << 6;
  const int m0 = blockIdx.y << 7, n0 = blockIdx.x << 7;

  f32x4 acc[4][4];
#pragma unroll
  for (int i = 0; i < 4; ++i)
#pragma unroll
    for (int j = 0; j < 4; ++j) acc[i][j] = (f32x4){0.f, 0.f, 0.f, 0.f};

  for (int k0 = 0; k0 < K; k0 += 64) {
#pragma unroll
    for (int i = 0; i < 4; ++i) {
      int c = i * 256 + tid;
      int row = c >> 3, pc = c & 7;
      int lc = pc ^ (row & 7);
      async_copy16(&As[c * 8], A + (size_t)(m0 + row) * K + k0 + lc * 8);
    }
#pragma unroll
    for (int i = 0; i < 4; ++i) {
      int c = i * 256 + tid;
      int row = c >> 3, pc = c & 7;
      int lc = pc ^ (row & 7);
      int br = n0 + row; br = br < N ? br : N - 1;
      async_copy16(&Bs[c * 8], B + (size_t)br * K + k0 + lc * 8);
    }
    asm volatile("s_waitcnt vmcnt(0)" ::: "memory");
    __syncthreads();

#pragma unroll
    for (int ks = 0; ks < 2; ++ks) {
      short8 af[4], bfr[4];
#pragma unroll
      for (int mi = 0; mi < 4; ++mi) {
        int row = wm + mi * 16 + lq;
        int ch = ((ks << 2) | lg) ^ (row & 7);
        af[mi] = *(const short8*)&As[row * 64 + ch * 8];
      }
#pragma unroll
      for (int ni = 0; ni < 4; ++ni) {
        int row = wn + ni * 16 + lq;
        int ch = ((ks << 2) | lg) ^ (row & 7);
        bfr[ni] = *(const short8*)&Bs[row * 64 + ch * 8];
      }
#pragma unroll
      for (int mi = 0; mi < 4; ++mi)
#pragma unroll
        for (int ni = 0; ni < 4; ++ni)
          acc[mi][ni] = mfma32(af[mi], bfr[ni], acc[mi][ni]);
    }
    __syncthreads();
  }

#pragma unroll
  for (int mi = 0; mi < 4; ++mi) {
#pragma unroll
    for (int ni = 0; ni < 4; ++ni) {
      int col = n0 + wn + ni * 16 + lq;
      if (col < N) {
#pragma unroll
        for (int r = 0; r < 4; ++r) {
          int rowm = m0 + wm + mi * 16 + lg * 4 + r;
          if constexpr (OUT_F32)
            ((float*)C)[(size_t)rowm * ldc + col] = acc[mi][ni][r];
          else
            ((u16*)C)[(size_t)rowm * ldc + col] = (u16)f2bf(acc[mi][ni][r]);
        }
      }
    }
  }
}

// ---------------- causal flash attention, LDS-staged ----------------
// grid (16, NH, B), block 256 (4 waves). chunk = b ? 15-bx : bx (triangle pairing).
// K staged [32 rows][24 chunks], chunk XOR-swizzled (linear LDS dest,
//   inverse-swizzled GLOBAL src, swizzled ds_read_b128).
// V staged [dsub8][ksub8][4][16] subtiles; consumed via ds_read_b64_tr_b16 with
//   lane addr = subtile_base + (lane&15)*8 BYTES (R3 bug: was (lane&15)*2).
__global__ __launch_bounds__(256) void attn_kernel(const u16* __restrict__ q,
                                                   const u16* __restrict__ qpe,
                                                   const u16* __restrict__ kv,
                                                   const u16* __restrict__ kpe,
                                                   u16* __restrict__ o) {
  __shared__ u16 Ks[2][32 * 192];   // 12 KB each
  __shared__ u16 Vs[2][32 * 128];   // 8 KB each
  const int S = 1024;
  const int tid = threadIdx.x;
  const int w = tid >> 6, l = tid & 63;
  const int lq = l & 15, lg = l >> 4;
  const int h = blockIdx.y, b = blockIdx.z;
  const int chunk = b ? (15 - (int)blockIdx.x) : (int)blockIdx.x;
  const int q0 = chunk * 64 + w * 16;
  const int nkt = chunk * 2 + 2;        // block-uniform tile count
  const size_t qrow = (size_t)b * S + q0 + lq;

  short8 qf[6];
#pragma unroll
  for (int c = 0; c < 4; ++c)
    qf[c] = *(const short8*)(q + qrow * 3072 + h * 192 + c * 32 + lg * 8);
#pragma unroll
  for (int c = 0; c < 2; ++c)
    qf[4 + c] = *(const short8*)(qpe + (qrow * 16 + h) * 64 + c * 32 + lg * 8);

  const size_t gb = (size_t)b * S;
  const u16* srcK[3]; int strK[3];
#pragma unroll
  for (int j = 0; j < 3; ++j) {
    int n = w * 192 + j * 64 + l;          // K chunk id, 0..767
    int row = (n * 2731) >> 16;            // n / 24
    int pc = n - row * 24;
    int lc = (pc & ~7) | ((pc & 7) ^ (row & 7));   // inverse swizzle on source
    if (lc < 16) { srcK[j] = kv + (gb + row) * 4096 + h * 256 + lc * 8; strK[j] = 32 * 4096; }
    else         { srcK[j] = kpe + (gb + row) * 64 + (lc - 16) * 8;     strK[j] = 32 * 64; }
  }
  const u16* srcV[2];
#pragma unroll
  for (int j = 0; j < 2; ++j) {
    int n = w * 128 + j * 64 + l;          // V chunk id, 0..511
    int dsub = n >> 6, m = n & 63;
    int ksub = m >> 3, r = (m >> 1) & 3, half = m & 1;
    srcV[j] = kv + (gb + ksub * 4 + r) * 4096 + h * 256 + 128 + dsub * 16 + half * 8;
  }

  auto stage = [&](int buf) {
#pragma unroll
    for (int j = 0; j < 3; ++j) {
      async_copy16(&Ks[buf][(w * 192 + j * 64) * 8], srcK[j]);
      srcK[j] += strK[j];
    }
#pragma unroll
    for (int j = 0; j < 2; ++j) {
      async_copy16(&Vs[buf][(w * 128 + j * 64) * 8], srcV[j]);
      srcV[j] += 32 * 4096;
    }
  };

  const float scl = 0.07216878364870323f * 1.4426950408889634f;  // 192^-0.5 * log2e
  float m2 = -INFINITY, lsum = 0.f;
  f32x4 oac[8];
#pragma unroll
  for (int dt = 0; dt < 8; ++dt) oac[dt] = (f32x4){0.f, 0.f, 0.f, 0.f};

  const int e0 = (lg ^ (lq & 7)) << 4;
  const int vbase = lg * 64 + lq * 4;     // u16 elements: subtile lg*128B + lane slot lq*8B

  stage(0);
  asm volatile("s_waitcnt vmcnt(0)" ::: "memory");
  __syncthreads();

  int buf = 0;
  for (int kt = 0; kt < nkt; ++kt) {
    if (kt + 1 < nkt) stage(buf ^ 1);   // prefetch next tile into other buffer

    // ---- QK^T: S^T[k, q] for 32 k-rows ----
    const char* kb = (const char*)&Ks[buf][0];
    f32x4 sac0, sac1;
#pragma unroll
    for (int kt2 = 0; kt2 < 2; ++kt2) {
      int a0 = (kt2 * 16 + lq) * 384 + e0;
      int a1 = a0 ^ 64;
      f32x4 s = (f32x4){0.f, 0.f, 0.f, 0.f};
      s = mfma32(*(const short8*)(kb + a0),       qf[0], s);
      s = mfma32(*(const short8*)(kb + a1),       qf[1], s);
      s = mfma32(*(const short8*)(kb + a0 + 128), qf[2], s);
      s = mfma32(*(const short8*)(kb + a1 + 128), qf[3], s);
      s = mfma32(*(const short8*)(kb + a0 + 256), qf[4], s);
      s = mfma32(*(const short8*)(kb + a1 + 256), qf[5], s);
      if (kt2 == 0) sac0 = s; else sac1 = s;
    }

    // ---- issue V transpose-reads ----
    short4v vf[8][2];
#pragma unroll
    for (int dt = 0; dt < 8; ++dt)
#pragma unroll
      for (int kt2 = 0; kt2 < 2; ++kt2)
        vf[dt][kt2] = tr_read16(&Vs[buf][vbase + dt * 512 + kt2 * 256]);

    // ---- online softmax (lane-local: q = q0+lq, k = kt*32 + kt2*16 + lg*4 + r) ----
    const int qi = q0 + lq;
    const int kb0 = kt * 32 + lg * 4;
    float s2[8];
#pragma unroll
    for (int r = 0; r < 4; ++r) {
      s2[r]     = (kb0 + r      <= qi) ? sac0[r] * scl : -INFINITY;
      s2[4 + r] = (kb0 + 16 + r <= qi) ? sac1[r] * scl : -INFINITY;
    }
    float mt = fmaxf(fmaxf(fmaxf(s2[0], s2[1]), fmaxf(s2[2], s2[3])),
                     fmaxf(fmaxf(s2[4], s2[5]), fmaxf(s2[6], s2[7])));
    mt = fmaxf(mt, __shfl_xor(mt, 16));
    mt = fmaxf(mt, __shfl_xor(mt, 32));
    float mnew = fmaxf(m2, mt);
    float resc = exp2f(m2 - mnew);     // 0 on first tile
    float p[8], psum = 0.f;
#pragma unroll
    for (int r = 0; r < 8; ++r) { p[r] = exp2f(s2[r] - mnew); psum += p[r]; }
    psum += __shfl_xor(psum, 16);
    psum += __shfl_xor(psum, 32);
    lsum = lsum * resc + psum;
    m2 = mnew;
    short4v pf0, pf1;
#pragma unroll
    for (int r = 0; r < 4; ++r) { pf0[r] = f2bf(p[r]); pf1[r] = f2bf(p[4 + r]); }

    // ---- wait V, then PV (rule 18: lgkmcnt + sched_barrier before reg-only MFMAs) ----
    asm volatile("s_waitcnt lgkmcnt(0)" ::: "memory");
    __builtin_amdgcn_sched_barrier(0);
#pragma unroll
    for (int dt = 0; dt < 8; ++dt) {
      f32x4 t = oac[dt];
      t[0] *= resc; t[1] *= resc; t[2] *= resc; t[3] *= resc;
      t = mfma16(vf[dt][0], pf0, t);
      t = mfma16(vf[dt][1], pf1, t);
      oac[dt] = t;
    }

    asm volatile("s_waitcnt vmcnt(0)" ::: "memory");
    __syncthreads();
    buf ^= 1;
  }

  float inv = 1.f / lsum;
#pragma unroll
  for (int dt = 0; dt < 8; ++dt)
#pragma unroll
    for (int r = 0; r < 4; ++r)
      o[((size_t)b * S + q0 + lq) * 2048 + h * 128 + dt * 16 + lg * 4 + r] =
          (u16)f2bf(oac[dt][r] * inv);
}

// ---------------- host launcher ----------------
extern "C" void kernel_launch(void* const* d_in, const int* in_sizes, int n_in,
                              void* d_out, int out_size, void* d_ws, size_t ws_size,
                              hipStream_t stream) {
  const float* h_in  = (const float*)d_in[0];
  const int*   pos   = (const int*)d_in[1];
  const float* qaw   = (const float*)d_in[2];
  const float* qaln  = (const float*)d_in[3];
  const float* qbw   = (const float*)d_in[4];
  const float* kvaw  = (const float*)d_in[5];
  const float* kvaln = (const float*)d_in[6];
  const float* kvbw  = (const float*)d_in[7];
  const float* ow    = (const float*)d_in[8];
  float* out = (float*)d_out;

  const int M = 2048;  // B*S
  char* p = (char*)d_ws;
  auto alloc = [&](size_t bytes) {
    char* r = p;
    p += (bytes + 255) & ~(size_t)255;
    return (u16*)r;
  };
  u16* h_bf = alloc((size_t)M * 2048 * 2);
  u16* W    = alloc((size_t)3072 * 1536 * 2);
  u16* qa   = alloc((size_t)M * 1536 * 2);
  u16* qbuf = alloc((size_t)M * 3072 * 2);
  u16* kvb  = alloc((size_t)M * 4096 * 2);
  u16* qpe  = alloc((size_t)M * 16 * 64 * 2);
  u16* kpe  = alloc((size_t)M * 64 * 2);
  u16* ckv  = qa;                                  // M x 576 (qa dead after gemm2)
  u16* ckvn = qa + (size_t)M * 576;                // M x 512
  u16* attno = h_bf;                               // M x 2048 (h_bf dead after gemm3)

  dim3 blk(256);

  cast_kernel<<<4096, blk, 0, stream>>>(h_in, h_bf, 1048576);
  cast_kernel<<<3072, blk, 0, stream>>>(qaw, W, 786432);
  gemm_bt<false><<<dim3(12, 16), blk, 0, stream>>>(h_bf, W, qa, M, 1536, 2048, 1536);
  rmsnorm_kernel<<<2048, 192, 0, stream>>>(qa, 1536, qa, 1536, qaln, 1536);

  cast_kernel<<<4608, blk, 0, stream>>>(qbw, W, 1179648);
  gemm_bt<false><<<dim3(24, 16), blk, 0, stream>>>(qa, W, qbuf, M, 3072, 1536, 3072);

  cast_kernel<<<1152, blk, 0, stream>>>(kvaw, W, 294912);
  gemm_bt<false><<<dim3(5, 16), blk, 0, stream>>>(h_bf, W, ckv, M, 576, 2048, 576);
  rmsnorm_kernel<<<2048, 64, 0, stream>>>(ckv, 576, ckvn, 512, kvaln, 512);

  cast_kernel<<<2048, blk, 0, stream>>>(kvbw, W, 524288);
  gemm_bt<false><<<dim3(32, 16), blk, 0, stream>>>(ckvn, W, kvb, M, 4096, 512, 4096);

  rope_kernel<<<2048, 64, 0, stream>>>(qbuf, ckv, pos, qpe, kpe);

  attn_kernel<<<dim3(16, 16, 2), blk, 0, stream>>>(qbuf, qpe, kvb, kpe, attno);

  cast_kernel<<<4096, blk, 0, stream>>>(ow, W, 1048576);
  gemm_bt<true><<<dim3(16, 16), blk, 0, stream>>>(attno, W, out, M, 2048, 2048, 2048);
}

// Round 5
// 226.723 us; speedup vs baseline: 1.5375x; 1.1679x over previous
//
#include <hip/hip_runtime.h>
#include <stdint.h>
#include <math.h>

typedef unsigned short u16;
typedef __attribute__((ext_vector_type(8))) short short8;   // 8 bf16 (4 VGPRs)
typedef __attribute__((ext_vector_type(4))) short short4v;  // 4 bf16 (2 VGPRs)
typedef __attribute__((ext_vector_type(4))) float f32x4;

#define DEVFN static __device__ __forceinline__

DEVFN float bf2f(short b) {
  union { unsigned int i; float f; } u;
  u.i = ((unsigned int)(unsigned short)b) << 16;
  return u.f;
}
DEVFN short f2bf(float f) {
  union { float f; unsigned int i; } u; u.f = f;
  unsigned int r = u.i + 0x7fffu + ((u.i >> 16) & 1u);  // RNE
  return (short)(r >> 16);
}

DEVFN f32x4 mfma32(short8 a, short8 b, f32x4 c) {
  return __builtin_amdgcn_mfma_f32_16x16x32_bf16(a, b, c, 0, 0, 0);
}
DEVFN f32x4 mfma16(short4v a, short4v b, f32x4 c) {
#if defined(__HIP_DEVICE_COMPILE__)
  return __builtin_amdgcn_mfma_f32_16x16x16bf16_1k(a, b, c, 0, 0, 0);
#else
  (void)a; (void)b; return c;  // host stub, never executed
#endif
}

typedef const __attribute__((address_space(1))) unsigned int* gp_t;
typedef __attribute__((address_space(3))) unsigned int* lp_t;
typedef const __attribute__((address_space(3))) u16* lds_cp;
DEVFN void async_copy16(u16* lds, const u16* g) {
  __builtin_amdgcn_global_load_lds((gp_t)(const void*)g, (lp_t)(void*)lds, 16, 0, 0);
}
// tr-read: 16-lane group reads a 4x16 bf16 row-major tile (128B); lane passes
// subtile_base + (lane&15)*8 bytes; output lane = column (lane&15), elem j = row j.
DEVFN short4v tr_read16(const u16* p) {
  short4v r;
  asm volatile("ds_read_b64_tr_b16 %0, %1" : "=v"(r) : "v"((lds_cp)(const void*)p));
  return r;
}

// ---------------- f32 -> bf16 cast ----------------
__global__ void cast_kernel(const float* __restrict__ in, u16* __restrict__ out, int n4) {
  int i = blockIdx.x * blockDim.x + threadIdx.x;
  if (i < n4) {
    f32x4 v = ((const f32x4*)in)[i];
    short4v o;
    o[0] = f2bf(v[0]); o[1] = f2bf(v[1]); o[2] = f2bf(v[2]); o[3] = f2bf(v[3]);
    ((short4v*)out)[i] = o;
  }
}

// ---------------- row-wise RMSNorm (bf16 in/out, f32 weight) ----------------
__global__ void rmsnorm_kernel(const u16* __restrict__ in, int istride,
                               u16* __restrict__ out, int ostride,
                               const float* __restrict__ w, int len) {
  const int row = blockIdx.x, t = threadIdx.x;
  short8 v = *(const short8*)(in + (size_t)row * istride + t * 8);
  float f[8]; float ss = 0.f;
#pragma unroll
  for (int j = 0; j < 8; ++j) { f[j] = bf2f(v[j]); ss += f[j] * f[j]; }
#pragma unroll
  for (int off = 1; off < 64; off <<= 1) ss += __shfl_xor(ss, off);
  __shared__ float red[8];
  int nw = (int)blockDim.x >> 6;
  if ((t & 63) == 0) red[t >> 6] = ss;
  __syncthreads();
  ss = 0.f;
  for (int i = 0; i < nw; ++i) ss += red[i];
  float r = rsqrtf(ss / (float)len + 1e-6f);
  const float* wp = w + t * 8;
  short8 ov;
#pragma unroll
  for (int j = 0; j < 8; ++j) ov[j] = f2bf(f[j] * r * wp[j]);
  *(short8*)(out + (size_t)row * ostride + t * 8) = ov;
}

// ---------------- RoPE (interleaved-perm variant) ----------------
__global__ void rope_kernel(const u16* __restrict__ q, const u16* __restrict__ ckv,
                            const int* __restrict__ pos_ids,
                            u16* __restrict__ qpe, u16* __restrict__ kpe) {
  const int row = blockIdx.x;
  const int t = threadIdx.x;
  const float pos = (float)pos_ids[row];
  const float L2TH = 13.287712379549449f;  // log2(10000)
  if (t < 32) {
    int i = t;
    float inv = exp2f(-L2TH * (float)i / 32.0f);
    float sv, cv; sincosf(pos * inv, &sv, &cv);
    float x0 = bf2f(ckv[(size_t)row * 576 + 512 + 2 * i]);
    float x1 = bf2f(ckv[(size_t)row * 576 + 512 + 2 * i + 1]);
    kpe[(size_t)row * 64 + i]      = (u16)f2bf(x0 * cv - x1 * sv);
    kpe[(size_t)row * 64 + 32 + i] = (u16)f2bf(x1 * cv + x0 * sv);
  }
#pragma unroll
  for (int j = 0; j < 8; ++j) {
    int idx = t + 64 * j;
    int hh = idx >> 5, i = idx & 31;
    float inv = exp2f(-L2TH * (float)i / 32.0f);
    float sv, cv; sincosf(pos * inv, &sv, &cv);
    const u16* base = q + (size_t)row * 3072 + hh * 192 + 128;
    float x0 = bf2f(base[2 * i]), x1 = bf2f(base[2 * i + 1]);
    u16* ob = qpe + ((size_t)row * 16 + hh) * 64;
    ob[i]      = (u16)f2bf(x0 * cv - x1 * sv);
    ob[32 + i] = (u16)f2bf(x1 * cv + x0 * sv);
  }
}

// ---------------- GEMM: C[m,n] = sum_k A[m,k]*B[n,k], bf16 in, f32 acc ----------------
// 128x64 tile (was 128x128): doubles grid -> 2-4 blocks/CU at this problem's shapes,
// so barrier/vmcnt(0) stalls overlap across blocks (was 1-2 blocks/CU, fully exposed).
template <bool OUT_F32>
__global__ __launch_bounds__(256) void gemm_bt(const u16* __restrict__ A,
                                               const u16* __restrict__ B,
                                               void* __restrict__ C,
                                               int M, int N, int K, int ldc) {
  __shared__ u16 As[128 * 64];
  __shared__ u16 Bs[64 * 64];
  const int tid = threadIdx.x;
  const int w = tid >> 6, l = tid & 63;
  const int lq = l & 15, lg = l >> 4;
  const int wm = (w >> 1) << 6;   // 0 or 64
  const int wn = (w & 1) << 5;    // 0 or 32
  const int m0 = blockIdx.y << 7, n0 = blockIdx.x << 6;

  f32x4 acc[4][2];
#pragma unroll
  for (int i = 0; i < 4; ++i)
#pragma unroll
    for (int j = 0; j < 2; ++j) acc[i][j] = (f32x4){0.f, 0.f, 0.f, 0.f};

  for (int k0 = 0; k0 < K; k0 += 64) {
#pragma unroll
    for (int i = 0; i < 4; ++i) {
      int c = i * 256 + tid;            // A: 1024 chunks of 16B
      int row = c >> 3, pc = c & 7;
      int lc = pc ^ (row & 7);
      async_copy16(&As[c * 8], A + (size_t)(m0 + row) * K + k0 + lc * 8);
    }
#pragma unroll
    for (int i = 0; i < 2; ++i) {
      int c = i * 256 + tid;            // B: 512 chunks
      int row = c >> 3, pc = c & 7;
      int lc = pc ^ (row & 7);
      async_copy16(&Bs[c * 8], B + (size_t)(n0 + row) * K + k0 + lc * 8);
    }
    asm volatile("s_waitcnt vmcnt(0)" ::: "memory");
    __syncthreads();

#pragma unroll
    for (int ks = 0; ks < 2; ++ks) {
      short8 af[4], bfr[2];
#pragma unroll
      for (int mi = 0; mi < 4; ++mi) {
        int row = wm + mi * 16 + lq;
        int ch = ((ks << 2) | lg) ^ (row & 7);
        af[mi] = *(const short8*)&As[row * 64 + ch * 8];
      }
#pragma unroll
      for (int ni = 0; ni < 2; ++ni) {
        int row = wn + ni * 16 + lq;
        int ch = ((ks << 2) | lg) ^ (row & 7);
        bfr[ni] = *(const short8*)&Bs[row * 64 + ch * 8];
      }
#pragma unroll
      for (int mi = 0; mi < 4; ++mi)
#pragma unroll
        for (int ni = 0; ni < 2; ++ni)
          acc[mi][ni] = mfma32(af[mi], bfr[ni], acc[mi][ni]);
    }
    __syncthreads();
  }

#pragma unroll
  for (int mi = 0; mi < 4; ++mi) {
#pragma unroll
    for (int ni = 0; ni < 2; ++ni) {
      int col = n0 + wn + ni * 16 + lq;
#pragma unroll
      for (int r = 0; r < 4; ++r) {
        int rowm = m0 + wm + mi * 16 + lg * 4 + r;
        if constexpr (OUT_F32)
          ((float*)C)[(size_t)rowm * ldc + col] = acc[mi][ni][r];
        else
          ((u16*)C)[(size_t)rowm * ldc + col] = (u16)f2bf(acc[mi][ni][r]);
      }
    }
  }
}

// ---------------- causal flash attention, LDS-staged, KVBLK=64 ----------------
// grid (16, NH, B), block 256 (4 waves), 64 q rows/block (wave = 16 q rows).
// One 64-k-row double-buffered tile per iteration: ONE barrier + ONE vmcnt(0)
// drain + ONE softmax/rescale pass per 64 k-rows (was per 32).
// K staged [64 rows][24 chunks], chunk XOR-swizzled; V staged [dsub8][ksub16][4][16]
// subtiles consumed via ds_read_b64_tr_b16 (lane addr = subtile + (lane&15)*8B).
__global__ __launch_bounds__(256) void attn_kernel(const u16* __restrict__ q,
                                                   const u16* __restrict__ qpe,
                                                   const u16* __restrict__ kv,
                                                   const u16* __restrict__ kpe,
                                                   u16* __restrict__ o) {
  __shared__ u16 Ks[2][64 * 192];   // 24 KB each
  __shared__ u16 Vs[2][64 * 128];   // 16 KB each
  const int S = 1024;
  const int tid = threadIdx.x;
  const int w = tid >> 6, l = tid & 63;
  const int lq = l & 15, lg = l >> 4;
  const int h = blockIdx.y, b = blockIdx.z;
  const int chunk = b ? (15 - (int)blockIdx.x) : (int)blockIdx.x;
  const int q0 = chunk * 64 + w * 16;
  const int nkt = chunk + 1;            // 64-row tiles, block-uniform
  const size_t qrow = (size_t)b * S + q0 + lq;

  short8 qf[6];
#pragma unroll
  for (int c = 0; c < 4; ++c)
    qf[c] = *(const short8*)(q + qrow * 3072 + h * 192 + c * 32 + lg * 8);
#pragma unroll
  for (int c = 0; c < 2; ++c)
    qf[4 + c] = *(const short8*)(qpe + (qrow * 16 + h) * 64 + c * 32 + lg * 8);

  const size_t gb = (size_t)b * S;
  const u16* srcK[6]; int strK[6];
#pragma unroll
  for (int j = 0; j < 6; ++j) {
    int n = w * 384 + j * 64 + l;          // K chunk id, 0..1535
    int row = (n * 2731) >> 16;            // n / 24 (exact for n < 16384)
    int pc = n - row * 24;
    int lc = (pc & ~7) | ((pc & 7) ^ (row & 7));   // inverse swizzle on source
    if (lc < 16) { srcK[j] = kv + (gb + row) * 4096 + h * 256 + lc * 8; strK[j] = 64 * 4096; }
    else         { srcK[j] = kpe + (gb + row) * 64 + (lc - 16) * 8;     strK[j] = 64 * 64; }
  }
  const u16* srcV[4];
#pragma unroll
  for (int j = 0; j < 4; ++j) {
    int n = w * 256 + j * 64 + l;          // V chunk id, 0..1023
    int s = n >> 3, hh = n & 7;
    int dsub = s >> 4, ksub = s & 15;      // subtile (dsub-major)
    int krow = hh >> 1, dhalf = hh & 1;
    srcV[j] = kv + (gb + ksub * 4 + krow) * 4096 + h * 256 + 128 + dsub * 16 + dhalf * 8;
  }

  auto stage = [&](int buf) {
#pragma unroll
    for (int j = 0; j < 6; ++j) {
      async_copy16(&Ks[buf][(w * 384 + j * 64) * 8], srcK[j]);
      srcK[j] += strK[j];
    }
#pragma unroll
    for (int j = 0; j < 4; ++j) {
      async_copy16(&Vs[buf][(w * 256 + j * 64) * 8], srcV[j]);
      srcV[j] += 64 * 4096;
    }
  };

  const float scl = 0.07216878364870323f * 1.4426950408889634f;  // 192^-0.5 * log2e
  float m2 = -INFINITY, lsum = 0.f;
  f32x4 oac[8];
#pragma unroll
  for (int dt = 0; dt < 8; ++dt) oac[dt] = (f32x4){0.f, 0.f, 0.f, 0.f};

  const int e0 = (lg ^ (lq & 7)) << 4;    // byte offset of swizzled chunk
  const int vbase = lg * 64 + lq * 4;     // u16: ksub-in-group lg + lane slot

  stage(0);
  asm volatile("s_waitcnt vmcnt(0)" ::: "memory");
  __syncthreads();

  int buf = 0;
  for (int kt = 0; kt < nkt; ++kt) {
    if (kt + 1 < nkt) stage(buf ^ 1);   // prefetch next 64-row tile

    // ---- QK^T: S^T[k, q] for 64 k-rows (row stride 384B) ----
    const char* kb = (const char*)&Ks[buf][0];
    f32x4 sac[4];
#pragma unroll
    for (int kt2 = 0; kt2 < 4; ++kt2) {
      int a0 = (kt2 * 16 + lq) * 384 + e0;
      int a1 = a0 ^ 64;
      f32x4 s = (f32x4){0.f, 0.f, 0.f, 0.f};
      s = mfma32(*(const short8*)(kb + a0),       qf[0], s);
      s = mfma32(*(const short8*)(kb + a1),       qf[1], s);
      s = mfma32(*(const short8*)(kb + a0 + 128), qf[2], s);
      s = mfma32(*(const short8*)(kb + a1 + 128), qf[3], s);
      s = mfma32(*(const short8*)(kb + a0 + 256), qf[4], s);
      s = mfma32(*(const short8*)(kb + a1 + 256), qf[5], s);
      sac[kt2] = s;
    }

    // ---- issue all V transpose-reads for the 64-row tile ----
    short4v vf[8][4];
#pragma unroll
    for (int dt = 0; dt < 8; ++dt)
#pragma unroll
      for (int kt2 = 0; kt2 < 4; ++kt2)
        vf[dt][kt2] = tr_read16(&Vs[buf][vbase + dt * 1024 + kt2 * 256]);

    // ---- online softmax over 16 lane-local values ----
    const int qi = q0 + lq;
    const int kb0 = kt * 64 + lg * 4;
    float s2[16];
#pragma unroll
    for (int kt2 = 0; kt2 < 4; ++kt2)
#pragma unroll
      for (int r = 0; r < 4; ++r)
        s2[kt2 * 4 + r] = (kb0 + kt2 * 16 + r <= qi) ? sac[kt2][r] * scl : -INFINITY;
    float mt = s2[0];
#pragma unroll
    for (int r = 1; r < 16; ++r) mt = fmaxf(mt, s2[r]);
    mt = fmaxf(mt, __shfl_xor(mt, 16));
    mt = fmaxf(mt, __shfl_xor(mt, 32));
    float mnew = fmaxf(m2, mt);
    float resc = exp2f(m2 - mnew);     // 0 on first tile
    float p[16], psum = 0.f;
#pragma unroll
    for (int r = 0; r < 16; ++r) { p[r] = exp2f(s2[r] - mnew); psum += p[r]; }
    psum += __shfl_xor(psum, 16);
    psum += __shfl_xor(psum, 32);
    lsum = lsum * resc + psum;
    m2 = mnew;
    short4v pf[4];
#pragma unroll
    for (int kt2 = 0; kt2 < 4; ++kt2)
#pragma unroll
      for (int r = 0; r < 4; ++r) pf[kt2][r] = f2bf(p[kt2 * 4 + r]);

    // ---- wait V, then PV (rule 18: lgkmcnt + sched_barrier before reg-only MFMAs) ----
    asm volatile("s_waitcnt lgkmcnt(0)" ::: "memory");
    __builtin_amdgcn_sched_barrier(0);
#pragma unroll
    for (int dt = 0; dt < 8; ++dt) {
      f32x4 t = oac[dt];
      t[0] *= resc; t[1] *= resc; t[2] *= resc; t[3] *= resc;
#pragma unroll
      for (int kt2 = 0; kt2 < 4; ++kt2) t = mfma16(vf[dt][kt2], pf[kt2], t);
      oac[dt] = t;
    }

    asm volatile("s_waitcnt vmcnt(0)" ::: "memory");
    __syncthreads();
    buf ^= 1;
  }

  float inv = 1.f / lsum;
#pragma unroll
  for (int dt = 0; dt < 8; ++dt)
#pragma unroll
    for (int r = 0; r < 4; ++r)
      o[((size_t)b * S + q0 + lq) * 2048 + h * 128 + dt * 16 + lg * 4 + r] =
          (u16)f2bf(oac[dt][r] * inv);
}

// ---------------- host launcher ----------------
extern "C" void kernel_launch(void* const* d_in, const int* in_sizes, int n_in,
                              void* d_out, int out_size, void* d_ws, size_t ws_size,
                              hipStream_t stream) {
  const float* h_in  = (const float*)d_in[0];
  const int*   pos   = (const int*)d_in[1];
  const float* qaw   = (const float*)d_in[2];
  const float* qaln  = (const float*)d_in[3];
  const float* qbw   = (const float*)d_in[4];
  const float* kvaw  = (const float*)d_in[5];
  const float* kvaln = (const float*)d_in[6];
  const float* kvbw  = (const float*)d_in[7];
  const float* ow    = (const float*)d_in[8];
  float* out = (float*)d_out;

  const int M = 2048;  // B*S
  char* p = (char*)d_ws;
  auto alloc = [&](size_t bytes) {
    char* r = p;
    p += (bytes + 255) & ~(size_t)255;
    return (u16*)r;
  };
  u16* h_bf = alloc((size_t)M * 2048 * 2);
  u16* W    = alloc((size_t)3072 * 1536 * 2);
  u16* qa   = alloc((size_t)M * 1536 * 2);
  u16* qbuf = alloc((size_t)M * 3072 * 2);
  u16* kvb  = alloc((size_t)M * 4096 * 2);
  u16* qpe  = alloc((size_t)M * 16 * 64 * 2);
  u16* kpe  = alloc((size_t)M * 64 * 2);
  u16* ckv  = qa;                                  // M x 576 (qa dead after gemm2)
  u16* ckvn = qa + (size_t)M * 576;                // M x 512
  u16* attno = h_bf;                               // M x 2048 (h_bf dead after gemm3)

  dim3 blk(256);

  cast_kernel<<<4096, blk, 0, stream>>>(h_in, h_bf, 1048576);
  cast_kernel<<<3072, blk, 0, stream>>>(qaw, W, 786432);
  gemm_bt<false><<<dim3(24, 16), blk, 0, stream>>>(h_bf, W, qa, M, 1536, 2048, 1536);
  rmsnorm_kernel<<<2048, 192, 0, stream>>>(qa, 1536, qa, 1536, qaln, 1536);

  cast_kernel<<<4608, blk, 0, stream>>>(qbw, W, 1179648);
  gemm_bt<false><<<dim3(48, 16), blk, 0, stream>>>(qa, W, qbuf, M, 3072, 1536, 3072);

  cast_kernel<<<1152, blk, 0, stream>>>(kvaw, W, 294912);
  gemm_bt<false><<<dim3(9, 16), blk, 0, stream>>>(h_bf, W, ckv, M, 576, 2048, 576);
  rmsnorm_kernel<<<2048, 64, 0, stream>>>(ckv, 576, ckvn, 512, kvaln, 512);

  cast_kernel<<<2048, blk, 0, stream>>>(kvbw, W, 524288);
  gemm_bt<false><<<dim3(64, 16), blk, 0, stream>>>(ckvn, W, kvb, M, 4096, 512, 4096);

  rope_kernel<<<2048, 64, 0, stream>>>(qbuf, ckv, pos, qpe, kpe);

  attn_kernel<<<dim3(16, 16, 2), blk, 0, stream>>>(qbuf, qpe, kvb, kpe, attno);

  cast_kernel<<<4096, blk, 0, stream>>>(ow, W, 1048576);
  gemm_bt<true><<<dim3(32, 16), blk, 0, stream>>>(attno, W, out, M, 2048, 2048, 2048);
}

// Round 6
// 215.737 us; speedup vs baseline: 1.6157x; 1.0509x over previous
//
#include <hip/hip_runtime.h>
#include <stdint.h>
#include <math.h>

typedef unsigned short u16;
typedef __attribute__((ext_vector_type(8))) short short8;   // 8 bf16 (4 VGPRs)
typedef __attribute__((ext_vector_type(4))) short short4v;  // 4 bf16 (2 VGPRs)
typedef __attribute__((ext_vector_type(4))) float f32x4;

#define DEVFN static __device__ __forceinline__

DEVFN float bf2f(short b) {
  union { unsigned int i; float f; } u;
  u.i = ((unsigned int)(unsigned short)b) << 16;
  return u.f;
}
DEVFN short f2bf(float f) {
  union { float f; unsigned int i; } u; u.f = f;
  unsigned int r = u.i + 0x7fffu + ((u.i >> 16) & 1u);  // RNE
  return (short)(r >> 16);
}

DEVFN f32x4 mfma32(short8 a, short8 b, f32x4 c) {
  return __builtin_amdgcn_mfma_f32_16x16x32_bf16(a, b, c, 0, 0, 0);
}
DEVFN f32x4 mfma16(short4v a, short4v b, f32x4 c) {
#if defined(__HIP_DEVICE_COMPILE__)
  return __builtin_amdgcn_mfma_f32_16x16x16bf16_1k(a, b, c, 0, 0, 0);
#else
  (void)a; (void)b; return c;  // host stub, never executed
#endif
}

typedef const __attribute__((address_space(1))) unsigned int* gp_t;
typedef __attribute__((address_space(3))) unsigned int* lp_t;
typedef const __attribute__((address_space(3))) u16* lds_cp;
DEVFN void async_copy16(u16* lds, const u16* g) {
  __builtin_amdgcn_global_load_lds((gp_t)(const void*)g, (lp_t)(void*)lds, 16, 0, 0);
}
// tr-read: 16-lane group reads a 4x16 bf16 row-major tile (128B); lane passes
// subtile_base + (lane&15)*8 bytes; output lane = column (lane&15), elem j = row j.
DEVFN short4v tr_read16(const u16* p) {
  short4v r;
  asm volatile("ds_read_b64_tr_b16 %0, %1" : "=v"(r) : "v"((lds_cp)(const void*)p));
  return r;
}

// ---------------- f32 -> bf16 cast ----------------
__global__ void cast_kernel(const float* __restrict__ in, u16* __restrict__ out, int n4) {
  int i = blockIdx.x * blockDim.x + threadIdx.x;
  if (i < n4) {
    f32x4 v = ((const f32x4*)in)[i];
    short4v o;
    o[0] = f2bf(v[0]); o[1] = f2bf(v[1]); o[2] = f2bf(v[2]); o[3] = f2bf(v[3]);
    ((short4v*)out)[i] = o;
  }
}

// ---------------- row-wise RMSNorm (bf16 in/out, f32 weight) ----------------
__global__ void rmsnorm_kernel(const u16* __restrict__ in, int istride,
                               u16* __restrict__ out, int ostride,
                               const float* __restrict__ w, int len) {
  const int row = blockIdx.x, t = threadIdx.x;
  short8 v = *(const short8*)(in + (size_t)row * istride + t * 8);
  float f[8]; float ss = 0.f;
#pragma unroll
  for (int j = 0; j < 8; ++j) { f[j] = bf2f(v[j]); ss += f[j] * f[j]; }
#pragma unroll
  for (int off = 1; off < 64; off <<= 1) ss += __shfl_xor(ss, off);
  __shared__ float red[8];
  int nw = (int)blockDim.x >> 6;
  if ((t & 63) == 0) red[t >> 6] = ss;
  __syncthreads();
  ss = 0.f;
  for (int i = 0; i < nw; ++i) ss += red[i];
  float r = rsqrtf(ss / (float)len + 1e-6f);
  const float* wp = w + t * 8;
  short8 ov;
#pragma unroll
  for (int j = 0; j < 8; ++j) ov[j] = f2bf(f[j] * r * wp[j]);
  *(short8*)(out + (size_t)row * ostride + t * 8) = ov;
}

// ---------------- RoPE (interleaved-perm variant) ----------------
__global__ void rope_kernel(const u16* __restrict__ q, const u16* __restrict__ ckv,
                            const int* __restrict__ pos_ids,
                            u16* __restrict__ qpe, u16* __restrict__ kpe) {
  const int row = blockIdx.x;
  const int t = threadIdx.x;
  const float pos = (float)pos_ids[row];
  const float L2TH = 13.287712379549449f;  // log2(10000)
  if (t < 32) {
    int i = t;
    float inv = exp2f(-L2TH * (float)i / 32.0f);
    float sv, cv; sincosf(pos * inv, &sv, &cv);
    float x0 = bf2f(ckv[(size_t)row * 576 + 512 + 2 * i]);
    float x1 = bf2f(ckv[(size_t)row * 576 + 512 + 2 * i + 1]);
    kpe[(size_t)row * 64 + i]      = (u16)f2bf(x0 * cv - x1 * sv);
    kpe[(size_t)row * 64 + 32 + i] = (u16)f2bf(x1 * cv + x0 * sv);
  }
#pragma unroll
  for (int j = 0; j < 8; ++j) {
    int idx = t + 64 * j;
    int hh = idx >> 5, i = idx & 31;
    float inv = exp2f(-L2TH * (float)i / 32.0f);
    float sv, cv; sincosf(pos * inv, &sv, &cv);
    const u16* base = q + (size_t)row * 3072 + hh * 192 + 128;
    float x0 = bf2f(base[2 * i]), x1 = bf2f(base[2 * i + 1]);
    u16* ob = qpe + ((size_t)row * 16 + hh) * 64;
    ob[i]      = (u16)f2bf(x0 * cv - x1 * sv);
    ob[32 + i] = (u16)f2bf(x1 * cv + x0 * sv);
  }
}

// ---------------- GEMM: C[m,n] = sum_k A[m,k]*B[n,k], bf16 in, f32 acc ----------------
// 128x64 tile, 4 waves. T3-minimal 2-phase prefetch: STAGE(t+1) issued BEFORE
// compute(t); one vmcnt(0)+barrier per K-step at the END, so next-tile loads fly
// during ds_read+MFMA instead of serializing (was: stage->drain->compute).
template <bool OUT_F32>
__global__ __launch_bounds__(256) void gemm_bt(const u16* __restrict__ A,
                                               const u16* __restrict__ B,
                                               void* __restrict__ C,
                                               int M, int N, int K, int ldc) {
  __shared__ u16 As[2][128 * 64];   // 16 KB each
  __shared__ u16 Bs[2][64 * 64];    // 8 KB each   -> 48 KB total, 3 blocks/CU
  const int tid = threadIdx.x;
  const int w = tid >> 6, l = tid & 63;
  const int lq = l & 15, lg = l >> 4;
  const int wm = (w >> 1) << 6;   // 0 or 64
  const int wn = (w & 1) << 5;    // 0 or 32
  const int m0 = blockIdx.y << 7, n0 = blockIdx.x << 6;

  // per-thread staging sources (advance by 64 u16 per K-step)
  const u16* srcA[4];
  int dstA[4];
#pragma unroll
  for (int i = 0; i < 4; ++i) {
    int c = i * 256 + tid;            // A chunk id 0..1023
    int row = c >> 3, pc = c & 7;
    int lc = pc ^ (row & 7);          // inverse swizzle on source
    srcA[i] = A + (size_t)(m0 + row) * K + lc * 8;
    dstA[i] = c * 8;
  }
  const u16* srcB[2];
  int dstB[2];
#pragma unroll
  for (int i = 0; i < 2; ++i) {
    int c = i * 256 + tid;            // B chunk id 0..511
    int row = c >> 3, pc = c & 7;
    int lc = pc ^ (row & 7);
    srcB[i] = B + (size_t)(n0 + row) * K + lc * 8;
    dstB[i] = c * 8;
  }

  auto stage = [&](int buf) {
#pragma unroll
    for (int i = 0; i < 4; ++i) {
      async_copy16(&As[buf][dstA[i]], srcA[i]);
      srcA[i] += 64;
    }
#pragma unroll
    for (int i = 0; i < 2; ++i) {
      async_copy16(&Bs[buf][dstB[i]], srcB[i]);
      srcB[i] += 64;
    }
  };

  f32x4 acc[4][2];
#pragma unroll
  for (int i = 0; i < 4; ++i)
#pragma unroll
    for (int j = 0; j < 2; ++j) acc[i][j] = (f32x4){0.f, 0.f, 0.f, 0.f};

  const int nt = K >> 6;
  stage(0);
  asm volatile("s_waitcnt vmcnt(0)" ::: "memory");
  __syncthreads();

  int buf = 0;
  for (int t = 0; t < nt; ++t) {
    if (t + 1 < nt) stage(buf ^ 1);   // issue next-tile loads; land during compute

#pragma unroll
    for (int ks = 0; ks < 2; ++ks) {
      short8 af[4], bfr[2];
#pragma unroll
      for (int mi = 0; mi < 4; ++mi) {
        int row = wm + mi * 16 + lq;
        int ch = ((ks << 2) | lg) ^ (row & 7);
        af[mi] = *(const short8*)&As[buf][row * 64 + ch * 8];
      }
#pragma unroll
      for (int ni = 0; ni < 2; ++ni) {
        int row = wn + ni * 16 + lq;
        int ch = ((ks << 2) | lg) ^ (row & 7);
        bfr[ni] = *(const short8*)&Bs[buf][row * 64 + ch * 8];
      }
#pragma unroll
      for (int mi = 0; mi < 4; ++mi)
#pragma unroll
        for (int ni = 0; ni < 2; ++ni)
          acc[mi][ni] = mfma32(af[mi], bfr[ni], acc[mi][ni]);
    }

    asm volatile("s_waitcnt vmcnt(0)" ::: "memory");  // next-tile loads (flew during MFMA)
    __syncthreads();                                   // all waves done reading buf
    buf ^= 1;
  }

#pragma unroll
  for (int mi = 0; mi < 4; ++mi) {
#pragma unroll
    for (int ni = 0; ni < 2; ++ni) {
      int col = n0 + wn + ni * 16 + lq;
#pragma unroll
      for (int r = 0; r < 4; ++r) {
        int rowm = m0 + wm + mi * 16 + lg * 4 + r;
        if constexpr (OUT_F32)
          ((float*)C)[(size_t)rowm * ldc + col] = acc[mi][ni][r];
        else
          ((u16*)C)[(size_t)rowm * ldc + col] = (u16)f2bf(acc[mi][ni][r]);
      }
    }
  }
}

// ---------------- causal flash attention, LDS-staged, KVBLK=64 ----------------
// grid (16, NH, B), block 256 (4 waves), 64 q rows/block (wave = 16 q rows).
// K staged [64 rows][24 chunks], chunk XOR-swizzled; V staged [dsub8][ksub16][4][16]
// subtiles consumed via ds_read_b64_tr_b16 (lane addr = subtile + (lane&15)*8B).
__global__ __launch_bounds__(256) void attn_kernel(const u16* __restrict__ q,
                                                   const u16* __restrict__ qpe,
                                                   const u16* __restrict__ kv,
                                                   const u16* __restrict__ kpe,
                                                   u16* __restrict__ o) {
  __shared__ u16 Ks[2][64 * 192];   // 24 KB each
  __shared__ u16 Vs[2][64 * 128];   // 16 KB each
  const int S = 1024;
  const int tid = threadIdx.x;
  const int w = tid >> 6, l = tid & 63;
  const int lq = l & 15, lg = l >> 4;
  const int h = blockIdx.y, b = blockIdx.z;
  const int chunk = b ? (15 - (int)blockIdx.x) : (int)blockIdx.x;
  const int q0 = chunk * 64 + w * 16;
  const int nkt = chunk + 1;            // 64-row tiles, block-uniform
  const size_t qrow = (size_t)b * S + q0 + lq;

  short8 qf[6];
#pragma unroll
  for (int c = 0; c < 4; ++c)
    qf[c] = *(const short8*)(q + qrow * 3072 + h * 192 + c * 32 + lg * 8);
#pragma unroll
  for (int c = 0; c < 2; ++c)
    qf[4 + c] = *(const short8*)(qpe + (qrow * 16 + h) * 64 + c * 32 + lg * 8);

  const size_t gb = (size_t)b * S;
  const u16* srcK[6]; int strK[6];
#pragma unroll
  for (int j = 0; j < 6; ++j) {
    int n = w * 384 + j * 64 + l;          // K chunk id, 0..1535
    int row = (n * 2731) >> 16;            // n / 24 (exact for n < 16384)
    int pc = n - row * 24;
    int lc = (pc & ~7) | ((pc & 7) ^ (row & 7));   // inverse swizzle on source
    if (lc < 16) { srcK[j] = kv + (gb + row) * 4096 + h * 256 + lc * 8; strK[j] = 64 * 4096; }
    else         { srcK[j] = kpe + (gb + row) * 64 + (lc - 16) * 8;     strK[j] = 64 * 64; }
  }
  const u16* srcV[4];
#pragma unroll
  for (int j = 0; j < 4; ++j) {
    int n = w * 256 + j * 64 + l;          // V chunk id, 0..1023
    int s = n >> 3, hh = n & 7;
    int dsub = s >> 4, ksub = s & 15;      // subtile (dsub-major)
    int krow = hh >> 1, dhalf = hh & 1;
    srcV[j] = kv + (gb + ksub * 4 + krow) * 4096 + h * 256 + 128 + dsub * 16 + dhalf * 8;
  }

  auto stage = [&](int buf) {
#pragma unroll
    for (int j = 0; j < 6; ++j) {
      async_copy16(&Ks[buf][(w * 384 + j * 64) * 8], srcK[j]);
      srcK[j] += strK[j];
    }
#pragma unroll
    for (int j = 0; j < 4; ++j) {
      async_copy16(&Vs[buf][(w * 256 + j * 64) * 8], srcV[j]);
      srcV[j] += 64 * 4096;
    }
  };

  const float scl = 0.07216878364870323f * 1.4426950408889634f;  // 192^-0.5 * log2e
  float m2 = -INFINITY, lsum = 0.f;
  f32x4 oac[8];
#pragma unroll
  for (int dt = 0; dt < 8; ++dt) oac[dt] = (f32x4){0.f, 0.f, 0.f, 0.f};

  const int e0 = (lg ^ (lq & 7)) << 4;    // byte offset of swizzled chunk
  const int vbase = lg * 64 + lq * 4;     // u16: ksub-in-group lg + lane slot

  stage(0);
  asm volatile("s_waitcnt vmcnt(0)" ::: "memory");
  __syncthreads();

  int buf = 0;
  for (int kt = 0; kt < nkt; ++kt) {
    if (kt + 1 < nkt) stage(buf ^ 1);   // prefetch next 64-row tile

    // ---- QK^T: S^T[k, q] for 64 k-rows (row stride 384B) ----
    const char* kb = (const char*)&Ks[buf][0];
    f32x4 sac[4];
#pragma unroll
    for (int kt2 = 0; kt2 < 4; ++kt2) {
      int a0 = (kt2 * 16 + lq) * 384 + e0;
      int a1 = a0 ^ 64;
      f32x4 s = (f32x4){0.f, 0.f, 0.f, 0.f};
      s = mfma32(*(const short8*)(kb + a0),       qf[0], s);
      s = mfma32(*(const short8*)(kb + a1),       qf[1], s);
      s = mfma32(*(const short8*)(kb + a0 + 128), qf[2], s);
      s = mfma32(*(const short8*)(kb + a1 + 128), qf[3], s);
      s = mfma32(*(const short8*)(kb + a0 + 256), qf[4], s);
      s = mfma32(*(const short8*)(kb + a1 + 256), qf[5], s);
      sac[kt2] = s;
    }

    // ---- issue all V transpose-reads for the 64-row tile ----
    short4v vf[8][4];
#pragma unroll
    for (int dt = 0; dt < 8; ++dt)
#pragma unroll
      for (int kt2 = 0; kt2 < 4; ++kt2)
        vf[dt][kt2] = tr_read16(&Vs[buf][vbase + dt * 1024 + kt2 * 256]);

    // ---- online softmax over 16 lane-local values ----
    const int qi = q0 + lq;
    const int kb0 = kt * 64 + lg * 4;
    float s2[16];
#pragma unroll
    for (int kt2 = 0; kt2 < 4; ++kt2)
#pragma unroll
      for (int r = 0; r < 4; ++r)
        s2[kt2 * 4 + r] = (kb0 + kt2 * 16 + r <= qi) ? sac[kt2][r] * scl : -INFINITY;
    float mt = s2[0];
#pragma unroll
    for (int r = 1; r < 16; ++r) mt = fmaxf(mt, s2[r]);
    mt = fmaxf(mt, __shfl_xor(mt, 16));
    mt = fmaxf(mt, __shfl_xor(mt, 32));
    float mnew = fmaxf(m2, mt);
    float resc = exp2f(m2 - mnew);     // 0 on first tile
    float p[16], psum = 0.f;
#pragma unroll
    for (int r = 0; r < 16; ++r) { p[r] = exp2f(s2[r] - mnew); psum += p[r]; }
    psum += __shfl_xor(psum, 16);
    psum += __shfl_xor(psum, 32);
    lsum = lsum * resc + psum;
    m2 = mnew;
    short4v pf[4];
#pragma unroll
    for (int kt2 = 0; kt2 < 4; ++kt2)
#pragma unroll
      for (int r = 0; r < 4; ++r) pf[kt2][r] = f2bf(p[kt2 * 4 + r]);

    // ---- wait V, then PV (rule 18: lgkmcnt + sched_barrier before reg-only MFMAs) ----
    asm volatile("s_waitcnt lgkmcnt(0)" ::: "memory");
    __builtin_amdgcn_sched_barrier(0);
#pragma unroll
    for (int dt = 0; dt < 8; ++dt) {
      f32x4 t = oac[dt];
      t[0] *= resc; t[1] *= resc; t[2] *= resc; t[3] *= resc;
#pragma unroll
      for (int kt2 = 0; kt2 < 4; ++kt2) t = mfma16(vf[dt][kt2], pf[kt2], t);
      oac[dt] = t;
    }

    asm volatile("s_waitcnt vmcnt(0)" ::: "memory");
    __syncthreads();
    buf ^= 1;
  }

  float inv = 1.f / lsum;
#pragma unroll
  for (int dt = 0; dt < 8; ++dt)
#pragma unroll
    for (int r = 0; r < 4; ++r)
      o[((size_t)b * S + q0 + lq) * 2048 + h * 128 + dt * 16 + lg * 4 + r] =
          (u16)f2bf(oac[dt][r] * inv);
}

// ---------------- host launcher ----------------
extern "C" void kernel_launch(void* const* d_in, const int* in_sizes, int n_in,
                              void* d_out, int out_size, void* d_ws, size_t ws_size,
                              hipStream_t stream) {
  const float* h_in  = (const float*)d_in[0];
  const int*   pos   = (const int*)d_in[1];
  const float* qaw   = (const float*)d_in[2];
  const float* qaln  = (const float*)d_in[3];
  const float* qbw   = (const float*)d_in[4];
  const float* kvaw  = (const float*)d_in[5];
  const float* kvaln = (const float*)d_in[6];
  const float* kvbw  = (const float*)d_in[7];
  const float* ow    = (const float*)d_in[8];
  float* out = (float*)d_out;

  const int M = 2048;  // B*S
  char* p = (char*)d_ws;
  auto alloc = [&](size_t bytes) {
    char* r = p;
    p += (bytes + 255) & ~(size_t)255;
    return (u16*)r;
  };
  u16* h_bf = alloc((size_t)M * 2048 * 2);
  u16* W    = alloc((size_t)3072 * 1536 * 2);
  u16* qa   = alloc((size_t)M * 1536 * 2);
  u16* qbuf = alloc((size_t)M * 3072 * 2);
  u16* kvb  = alloc((size_t)M * 4096 * 2);
  u16* qpe  = alloc((size_t)M * 16 * 64 * 2);
  u16* kpe  = alloc((size_t)M * 64 * 2);
  u16* ckv  = qa;                                  // M x 576 (qa dead after gemm2)
  u16* ckvn = qa + (size_t)M * 576;                // M x 512
  u16* attno = h_bf;                               // M x 2048 (h_bf dead after gemm3)

  dim3 blk(256);

  cast_kernel<<<4096, blk, 0, stream>>>(h_in, h_bf, 1048576);
  cast_kernel<<<3072, blk, 0, stream>>>(qaw, W, 786432);
  gemm_bt<false><<<dim3(24, 16), blk, 0, stream>>>(h_bf, W, qa, M, 1536, 2048, 1536);
  rmsnorm_kernel<<<2048, 192, 0, stream>>>(qa, 1536, qa, 1536, qaln, 1536);

  cast_kernel<<<4608, blk, 0, stream>>>(qbw, W, 1179648);
  gemm_bt<false><<<dim3(48, 16), blk, 0, stream>>>(qa, W, qbuf, M, 3072, 1536, 3072);

  cast_kernel<<<1152, blk, 0, stream>>>(kvaw, W, 294912);
  gemm_bt<false><<<dim3(9, 16), blk, 0, stream>>>(h_bf, W, ckv, M, 576, 2048, 576);
  rmsnorm_kernel<<<2048, 64, 0, stream>>>(ckv, 576, ckvn, 512, kvaln, 512);

  cast_kernel<<<2048, blk, 0, stream>>>(kvbw, W, 524288);
  gemm_bt<false><<<dim3(64, 16), blk, 0, stream>>>(ckvn, W, kvb, M, 4096, 512, 4096);

  rope_kernel<<<2048, 64, 0, stream>>>(qbuf, ckv, pos, qpe, kpe);

  attn_kernel<<<dim3(16, 16, 2), blk, 0, stream>>>(qbuf, qpe, kvb, kpe, attno);

  cast_kernel<<<4096, blk, 0, stream>>>(ow, W, 1048576);
  gemm_bt<true><<<dim3(32, 16), blk, 0, stream>>>(attno, W, out, M, 2048, 2048, 2048);
}

// Round 7
// 206.402 us; speedup vs baseline: 1.6888x; 1.0452x over previous
//
#include <hip/hip_runtime.h>
#include <stdint.h>
#include <math.h>

typedef unsigned short u16;
typedef __attribute__((ext_vector_type(8))) short short8;   // 8 bf16 (4 VGPRs)
typedef __attribute__((ext_vector_type(4))) short short4v;  // 4 bf16 (2 VGPRs)
typedef __attribute__((ext_vector_type(4))) float f32x4;

#define DEVFN static __device__ __forceinline__

DEVFN float bf2f(short b) {
  union { unsigned int i; float f; } u;
  u.i = ((unsigned int)(unsigned short)b) << 16;
  return u.f;
}
DEVFN short f2bf(float f) {
  union { float f; unsigned int i; } u; u.f = f;
  unsigned int r = u.i + 0x7fffu + ((u.i >> 16) & 1u);  // RNE
  return (short)(r >> 16);
}

DEVFN f32x4 mfma32(short8 a, short8 b, f32x4 c) {
  return __builtin_amdgcn_mfma_f32_16x16x32_bf16(a, b, c, 0, 0, 0);
}
DEVFN f32x4 mfma16(short4v a, short4v b, f32x4 c) {
#if defined(__HIP_DEVICE_COMPILE__)
  return __builtin_amdgcn_mfma_f32_16x16x16bf16_1k(a, b, c, 0, 0, 0);
#else
  (void)a; (void)b; return c;  // host stub, never executed
#endif
}

typedef const __attribute__((address_space(1))) unsigned int* gp_t;
typedef __attribute__((address_space(3))) unsigned int* lp_t;
typedef const __attribute__((address_space(3))) u16* lds_cp;
DEVFN void async_copy16(u16* lds, const u16* g) {
  __builtin_amdgcn_global_load_lds((gp_t)(const void*)g, (lp_t)(void*)lds, 16, 0, 0);
}
// tr-read: 16-lane group reads a 4x16 bf16 row-major tile (128B); lane passes
// subtile_base + (lane&15)*8 bytes; output lane = column (lane&15), elem j = row j.
DEVFN short4v tr_read16(const u16* p) {
  short4v r;
  asm volatile("ds_read_b64_tr_b16 %0, %1" : "=v"(r) : "v"((lds_cp)(const void*)p));
  return r;
}
DEVFN void raw_barrier() {
  asm volatile("" ::: "memory");
  __builtin_amdgcn_s_barrier();
  asm volatile("" ::: "memory");
}

// ---------------- f32 -> bf16 cast ----------------
__global__ void cast_kernel(const float* __restrict__ in, u16* __restrict__ out, int n4) {
  int i = blockIdx.x * blockDim.x + threadIdx.x;
  if (i < n4) {
    f32x4 v = ((const f32x4*)in)[i];
    short4v o;
    o[0] = f2bf(v[0]); o[1] = f2bf(v[1]); o[2] = f2bf(v[2]); o[3] = f2bf(v[3]);
    ((short4v*)out)[i] = o;
  }
}

// ---------------- row-wise RMSNorm (bf16 in/out, f32 weight) ----------------
__global__ void rmsnorm_kernel(const u16* __restrict__ in, int istride,
                               u16* __restrict__ out, int ostride,
                               const float* __restrict__ w, int len) {
  const int row = blockIdx.x, t = threadIdx.x;
  short8 v = *(const short8*)(in + (size_t)row * istride + t * 8);
  float f[8]; float ss = 0.f;
#pragma unroll
  for (int j = 0; j < 8; ++j) { f[j] = bf2f(v[j]); ss += f[j] * f[j]; }
#pragma unroll
  for (int off = 1; off < 64; off <<= 1) ss += __shfl_xor(ss, off);
  __shared__ float red[8];
  int nw = (int)blockDim.x >> 6;
  if ((t & 63) == 0) red[t >> 6] = ss;
  __syncthreads();
  ss = 0.f;
  for (int i = 0; i < nw; ++i) ss += red[i];
  float r = rsqrtf(ss / (float)len + 1e-6f);
  const float* wp = w + t * 8;
  short8 ov;
#pragma unroll
  for (int j = 0; j < 8; ++j) ov[j] = f2bf(f[j] * r * wp[j]);
  *(short8*)(out + (size_t)row * ostride + t * 8) = ov;
}

// ---------------- RoPE (interleaved-perm variant) ----------------
__global__ void rope_kernel(const u16* __restrict__ q, const u16* __restrict__ ckv,
                            const int* __restrict__ pos_ids,
                            u16* __restrict__ qpe, u16* __restrict__ kpe) {
  const int row = blockIdx.x;
  const int t = threadIdx.x;
  const float pos = (float)pos_ids[row];
  const float L2TH = 13.287712379549449f;  // log2(10000)
  if (t < 32) {
    int i = t;
    float inv = exp2f(-L2TH * (float)i / 32.0f);
    float sv, cv; sincosf(pos * inv, &sv, &cv);
    float x0 = bf2f(ckv[(size_t)row * 576 + 512 + 2 * i]);
    float x1 = bf2f(ckv[(size_t)row * 576 + 512 + 2 * i + 1]);
    kpe[(size_t)row * 64 + i]      = (u16)f2bf(x0 * cv - x1 * sv);
    kpe[(size_t)row * 64 + 32 + i] = (u16)f2bf(x1 * cv + x0 * sv);
  }
#pragma unroll
  for (int j = 0; j < 8; ++j) {
    int idx = t + 64 * j;
    int hh = idx >> 5, i = idx & 31;
    float inv = exp2f(-L2TH * (float)i / 32.0f);
    float sv, cv; sincosf(pos * inv, &sv, &cv);
    const u16* base = q + (size_t)row * 3072 + hh * 192 + 128;
    float x0 = bf2f(base[2 * i]), x1 = bf2f(base[2 * i + 1]);
    u16* ob = qpe + ((size_t)row * 16 + hh) * 64;
    ob[i]      = (u16)f2bf(x0 * cv - x1 * sv);
    ob[32 + i] = (u16)f2bf(x1 * cv + x0 * sv);
  }
}

// ---------------- GEMM: C[m,n] = sum_k A[m,k]*B[n,k], bf16 in, f32 acc ----------------
// BMx64 tile, 4 waves. T4 counted-vmcnt 2-deep pipeline (m218 recipe): raw
// s_barrier (NOT __syncthreads -- hipcc drains vmcnt(0) there), wait vmcnt(LOADS)
// so the NEXT tile's loads stay in flight across the barrier. Schedule:
//   prologue: stage(t0,buf0), stage(t1,buf1)
//   iter t:  vmcnt(LOADS | 0 if last) -> barrier -> compute(buf) -> barrier
//            -> stage(t+2, buf)   [overwrite safe: all waves past compute]
// TAG only differentiates kernel names in rocprof.
template <int BM, bool OUT_F32, int TAG>
__global__ __launch_bounds__(256) void gemm_bt(const u16* __restrict__ A,
                                               const u16* __restrict__ B,
                                               void* __restrict__ C,
                                               int M, int N, int K, int ldc) {
  constexpr int ACH = BM / 32;      // per-thread A chunks (BM*64 u16 / 256t / 8)
  constexpr int MI  = BM / 32;      // m-frags per wave (wave covers BM/2 rows)
  __shared__ u16 As[2][BM * 64];
  __shared__ u16 Bs[2][64 * 64];
  const int tid = threadIdx.x;
  const int w = tid >> 6, l = tid & 63;
  const int lq = l & 15, lg = l >> 4;
  const int wm = (w >> 1) * (BM / 2);
  const int wn = (w & 1) << 5;
  const int m0 = blockIdx.y * BM, n0 = blockIdx.x << 6;

  const u16* srcA[ACH]; int dstA[ACH];
#pragma unroll
  for (int i = 0; i < ACH; ++i) {
    int c = i * 256 + tid;
    int row = c >> 3, pc = c & 7;
    int lc = pc ^ (row & 7);          // inverse swizzle on source
    srcA[i] = A + (size_t)(m0 + row) * K + lc * 8;
    dstA[i] = c * 8;
  }
  const u16* srcB[2]; int dstB[2];
#pragma unroll
  for (int i = 0; i < 2; ++i) {
    int c = i * 256 + tid;
    int row = c >> 3, pc = c & 7;
    int lc = pc ^ (row & 7);
    srcB[i] = B + (size_t)(n0 + row) * K + lc * 8;
    dstB[i] = c * 8;
  }

  auto stage = [&](int buf) {
#pragma unroll
    for (int i = 0; i < ACH; ++i) {
      async_copy16(&As[buf][dstA[i]], srcA[i]);
      srcA[i] += 64;
    }
#pragma unroll
    for (int i = 0; i < 2; ++i) {
      async_copy16(&Bs[buf][dstB[i]], srcB[i]);
      srcB[i] += 64;
    }
  };

  f32x4 acc[MI][2];
#pragma unroll
  for (int i = 0; i < MI; ++i)
#pragma unroll
    for (int j = 0; j < 2; ++j) acc[i][j] = (f32x4){0.f, 0.f, 0.f, 0.f};

  const int nt = K >> 6;
  stage(0);
  if (nt > 1) stage(1);

  for (int t = 0; t < nt; ++t) {
    if (t + 1 < nt) {
      if constexpr (BM == 128)
        asm volatile("s_waitcnt vmcnt(6)" ::: "memory");
      else
        asm volatile("s_waitcnt vmcnt(4)" ::: "memory");
    } else {
      asm volatile("s_waitcnt vmcnt(0)" ::: "memory");
    }
    raw_barrier();                     // tile t visible to all waves

    const int buf = t & 1;
#pragma unroll
    for (int ks = 0; ks < 2; ++ks) {
      short8 af[MI], bfr[2];
#pragma unroll
      for (int mi = 0; mi < MI; ++mi) {
        int row = wm + mi * 16 + lq;
        int ch = ((ks << 2) | lg) ^ (row & 7);
        af[mi] = *(const short8*)&As[buf][row * 64 + ch * 8];
      }
#pragma unroll
      for (int ni = 0; ni < 2; ++ni) {
        int row = wn + ni * 16 + lq;
        int ch = ((ks << 2) | lg) ^ (row & 7);
        bfr[ni] = *(const short8*)&Bs[buf][row * 64 + ch * 8];
      }
#pragma unroll
      for (int mi = 0; mi < MI; ++mi)
#pragma unroll
        for (int ni = 0; ni < 2; ++ni)
          acc[mi][ni] = mfma32(af[mi], bfr[ni], acc[mi][ni]);
    }

    raw_barrier();                     // all waves done reading buf
    if (t + 2 < nt) stage(buf);        // refill it 2 tiles ahead
  }

#pragma unroll
  for (int mi = 0; mi < MI; ++mi) {
#pragma unroll
    for (int ni = 0; ni < 2; ++ni) {
      int col = n0 + wn + ni * 16 + lq;
#pragma unroll
      for (int r = 0; r < 4; ++r) {
        int rowm = m0 + wm + mi * 16 + lg * 4 + r;
        if constexpr (OUT_F32)
          ((float*)C)[(size_t)rowm * ldc + col] = acc[mi][ni][r];
        else
          ((u16*)C)[(size_t)rowm * ldc + col] = (u16)f2bf(acc[mi][ni][r]);
      }
    }
  }
}

// ---------------- causal flash attention, LDS-staged, KVBLK=64 ----------------
// grid (16, NH, B), block 256 (4 waves), 64 q rows/block (wave = 16 q rows).
// K staged [64 rows][24 chunks], chunk XOR-swizzled; V staged [dsub8][ksub16][4][16]
// subtiles consumed via ds_read_b64_tr_b16 (lane addr = subtile + (lane&15)*8B).
__global__ __launch_bounds__(256) void attn_kernel(const u16* __restrict__ q,
                                                   const u16* __restrict__ qpe,
                                                   const u16* __restrict__ kv,
                                                   const u16* __restrict__ kpe,
                                                   u16* __restrict__ o) {
  __shared__ u16 Ks[2][64 * 192];   // 24 KB each
  __shared__ u16 Vs[2][64 * 128];   // 16 KB each
  const int S = 1024;
  const int tid = threadIdx.x;
  const int w = tid >> 6, l = tid & 63;
  const int lq = l & 15, lg = l >> 4;
  const int h = blockIdx.y, b = blockIdx.z;
  const int chunk = b ? (15 - (int)blockIdx.x) : (int)blockIdx.x;
  const int q0 = chunk * 64 + w * 16;
  const int nkt = chunk + 1;            // 64-row tiles, block-uniform
  const size_t qrow = (size_t)b * S + q0 + lq;

  short8 qf[6];
#pragma unroll
  for (int c = 0; c < 4; ++c)
    qf[c] = *(const short8*)(q + qrow * 3072 + h * 192 + c * 32 + lg * 8);
#pragma unroll
  for (int c = 0; c < 2; ++c)
    qf[4 + c] = *(const short8*)(qpe + (qrow * 16 + h) * 64 + c * 32 + lg * 8);

  const size_t gb = (size_t)b * S;
  const u16* srcK[6]; int strK[6];
#pragma unroll
  for (int j = 0; j < 6; ++j) {
    int n = w * 384 + j * 64 + l;          // K chunk id, 0..1535
    int row = (n * 2731) >> 16;            // n / 24 (exact for n < 16384)
    int pc = n - row * 24;
    int lc = (pc & ~7) | ((pc & 7) ^ (row & 7));   // inverse swizzle on source
    if (lc < 16) { srcK[j] = kv + (gb + row) * 4096 + h * 256 + lc * 8; strK[j] = 64 * 4096; }
    else         { srcK[j] = kpe + (gb + row) * 64 + (lc - 16) * 8;     strK[j] = 64 * 64; }
  }
  const u16* srcV[4];
#pragma unroll
  for (int j = 0; j < 4; ++j) {
    int n = w * 256 + j * 64 + l;          // V chunk id, 0..1023
    int s = n >> 3, hh = n & 7;
    int dsub = s >> 4, ksub = s & 15;      // subtile (dsub-major)
    int krow = hh >> 1, dhalf = hh & 1;
    srcV[j] = kv + (gb + ksub * 4 + krow) * 4096 + h * 256 + 128 + dsub * 16 + dhalf * 8;
  }

  auto stage = [&](int buf) {
#pragma unroll
    for (int j = 0; j < 6; ++j) {
      async_copy16(&Ks[buf][(w * 384 + j * 64) * 8], srcK[j]);
      srcK[j] += strK[j];
    }
#pragma unroll
    for (int j = 0; j < 4; ++j) {
      async_copy16(&Vs[buf][(w * 256 + j * 64) * 8], srcV[j]);
      srcV[j] += 64 * 4096;
    }
  };

  const float scl = 0.07216878364870323f * 1.4426950408889634f;  // 192^-0.5 * log2e
  float m2 = -INFINITY, lsum = 0.f;
  f32x4 oac[8];
#pragma unroll
  for (int dt = 0; dt < 8; ++dt) oac[dt] = (f32x4){0.f, 0.f, 0.f, 0.f};

  const int e0 = (lg ^ (lq & 7)) << 4;    // byte offset of swizzled chunk
  const int vbase = lg * 64 + lq * 4;     // u16: ksub-in-group lg + lane slot

  stage(0);
  asm volatile("s_waitcnt vmcnt(0)" ::: "memory");
  __syncthreads();

  int buf = 0;
  for (int kt = 0; kt < nkt; ++kt) {
    if (kt + 1 < nkt) stage(buf ^ 1);   // prefetch next 64-row tile

    // ---- QK^T: S^T[k, q] for 64 k-rows (row stride 384B) ----
    const char* kb = (const char*)&Ks[buf][0];
    f32x4 sac[4];
#pragma unroll
    for (int kt2 = 0; kt2 < 4; ++kt2) {
      int a0 = (kt2 * 16 + lq) * 384 + e0;
      int a1 = a0 ^ 64;
      f32x4 s = (f32x4){0.f, 0.f, 0.f, 0.f};
      s = mfma32(*(const short8*)(kb + a0),       qf[0], s);
      s = mfma32(*(const short8*)(kb + a1),       qf[1], s);
      s = mfma32(*(const short8*)(kb + a0 + 128), qf[2], s);
      s = mfma32(*(const short8*)(kb + a1 + 128), qf[3], s);
      s = mfma32(*(const short8*)(kb + a0 + 256), qf[4], s);
      s = mfma32(*(const short8*)(kb + a1 + 256), qf[5], s);
      sac[kt2] = s;
    }

    // ---- issue all V transpose-reads for the 64-row tile ----
    short4v vf[8][4];
#pragma unroll
    for (int dt = 0; dt < 8; ++dt)
#pragma unroll
      for (int kt2 = 0; kt2 < 4; ++kt2)
        vf[dt][kt2] = tr_read16(&Vs[buf][vbase + dt * 1024 + kt2 * 256]);

    // ---- online softmax over 16 lane-local values ----
    const int qi = q0 + lq;
    const int kb0 = kt * 64 + lg * 4;
    float s2[16];
#pragma unroll
    for (int kt2 = 0; kt2 < 4; ++kt2)
#pragma unroll
      for (int r = 0; r < 4; ++r)
        s2[kt2 * 4 + r] = (kb0 + kt2 * 16 + r <= qi) ? sac[kt2][r] * scl : -INFINITY;
    float mt = s2[0];
#pragma unroll
    for (int r = 1; r < 16; ++r) mt = fmaxf(mt, s2[r]);
    mt = fmaxf(mt, __shfl_xor(mt, 16));
    mt = fmaxf(mt, __shfl_xor(mt, 32));
    float mnew = fmaxf(m2, mt);
    float resc = exp2f(m2 - mnew);     // 0 on first tile
    float p[16], psum = 0.f;
#pragma unroll
    for (int r = 0; r < 16; ++r) { p[r] = exp2f(s2[r] - mnew); psum += p[r]; }
    psum += __shfl_xor(psum, 16);
    psum += __shfl_xor(psum, 32);
    lsum = lsum * resc + psum;
    m2 = mnew;
    short4v pf[4];
#pragma unroll
    for (int kt2 = 0; kt2 < 4; ++kt2)
#pragma unroll
      for (int r = 0; r < 4; ++r) pf[kt2][r] = f2bf(p[kt2 * 4 + r]);

    // ---- wait V, then PV (rule 18: lgkmcnt + sched_barrier before reg-only MFMAs) ----
    asm volatile("s_waitcnt lgkmcnt(0)" ::: "memory");
    __builtin_amdgcn_sched_barrier(0);
#pragma unroll
    for (int dt = 0; dt < 8; ++dt) {
      f32x4 t = oac[dt];
      t[0] *= resc; t[1] *= resc; t[2] *= resc; t[3] *= resc;
#pragma unroll
      for (int kt2 = 0; kt2 < 4; ++kt2) t = mfma16(vf[dt][kt2], pf[kt2], t);
      oac[dt] = t;
    }

    asm volatile("s_waitcnt vmcnt(0)" ::: "memory");
    __syncthreads();
    buf ^= 1;
  }

  float inv = 1.f / lsum;
#pragma unroll
  for (int dt = 0; dt < 8; ++dt)
#pragma unroll
    for (int r = 0; r < 4; ++r)
      o[((size_t)b * S + q0 + lq) * 2048 + h * 128 + dt * 16 + lg * 4 + r] =
          (u16)f2bf(oac[dt][r] * inv);
}

// ---------------- host launcher ----------------
extern "C" void kernel_launch(void* const* d_in, const int* in_sizes, int n_in,
                              void* d_out, int out_size, void* d_ws, size_t ws_size,
                              hipStream_t stream) {
  const float* h_in  = (const float*)d_in[0];
  const int*   pos   = (const int*)d_in[1];
  const float* qaw   = (const float*)d_in[2];
  const float* qaln  = (const float*)d_in[3];
  const float* qbw   = (const float*)d_in[4];
  const float* kvaw  = (const float*)d_in[5];
  const float* kvaln = (const float*)d_in[6];
  const float* kvbw  = (const float*)d_in[7];
  const float* ow    = (const float*)d_in[8];
  float* out = (float*)d_out;

  const int M = 2048;  // B*S
  char* p = (char*)d_ws;
  auto alloc = [&](size_t bytes) {
    char* r = p;
    p += (bytes + 255) & ~(size_t)255;
    return (u16*)r;
  };
  u16* h_bf = alloc((size_t)M * 2048 * 2);
  u16* W    = alloc((size_t)3072 * 1536 * 2);
  u16* qa   = alloc((size_t)M * 1536 * 2);
  u16* qbuf = alloc((size_t)M * 3072 * 2);
  u16* kvb  = alloc((size_t)M * 4096 * 2);
  u16* qpe  = alloc((size_t)M * 16 * 64 * 2);
  u16* kpe  = alloc((size_t)M * 64 * 2);
  u16* ckv  = qa;                                  // M x 576 (qa dead after gemm2)
  u16* ckvn = qa + (size_t)M * 576;                // M x 512
  u16* attno = h_bf;                               // M x 2048 (h_bf dead after gemm3)

  dim3 blk(256);

  cast_kernel<<<4096, blk, 0, stream>>>(h_in, h_bf, 1048576);
  cast_kernel<<<3072, blk, 0, stream>>>(qaw, W, 786432);
  gemm_bt<128, false, 1><<<dim3(24, 16), blk, 0, stream>>>(h_bf, W, qa, M, 1536, 2048, 1536);
  rmsnorm_kernel<<<2048, 192, 0, stream>>>(qa, 1536, qa, 1536, qaln, 1536);

  cast_kernel<<<4608, blk, 0, stream>>>(qbw, W, 1179648);
  gemm_bt<128, false, 2><<<dim3(48, 16), blk, 0, stream>>>(qa, W, qbuf, M, 3072, 1536, 3072);

  cast_kernel<<<1152, blk, 0, stream>>>(kvaw, W, 294912);
  gemm_bt<64, false, 3><<<dim3(9, 32), blk, 0, stream>>>(h_bf, W, ckv, M, 576, 2048, 576);
  rmsnorm_kernel<<<2048, 64, 0, stream>>>(ckv, 576, ckvn, 512, kvaln, 512);

  cast_kernel<<<2048, blk, 0, stream>>>(kvbw, W, 524288);
  gemm_bt<128, false, 4><<<dim3(64, 16), blk, 0, stream>>>(ckvn, W, kvb, M, 4096, 512, 4096);

  rope_kernel<<<2048, 64, 0, stream>>>(qbuf, ckv, pos, qpe, kpe);

  attn_kernel<<<dim3(16, 16, 2), blk, 0, stream>>>(qbuf, qpe, kvb, kpe, attno);

  cast_kernel<<<4096, blk, 0, stream>>>(ow, W, 1048576);
  gemm_bt<128, true, 5><<<dim3(32, 16), blk, 0, stream>>>(attno, W, out, M, 2048, 2048, 2048);
}